// Round 5
// baseline (325.109 us; speedup 1.0000x reference)
//
#include <hip/hip_runtime.h>
#include <math.h>

typedef __bf16 bf16_t;
typedef bf16_t bf16x8 __attribute__((ext_vector_type(8)));
typedef float f32x16 __attribute__((ext_vector_type(16)));
typedef unsigned int u32x4 __attribute__((ext_vector_type(4)));

#define MFMA32(a, b, c) __builtin_amdgcn_mfma_f32_32x32x16_bf16(a, b, c, 0, 0, 0)
#define ROWOF(r, h) (((r) & 3) + 8 * ((r) >> 2) + 4 * (h))

// ---- problem constants ----
// B=4, C=512, H=W=64, WS=32, NH=8 heads, DH=64, GROUPS=32 (16 ch/group)
// windows: 16 total (b*4 + wh*2 + ww), tokens n=1024 per window

// ---- workspace layout (bytes) ----
static constexpr size_t OFF_STATS = 0;                        // 128*2 f32
static constexpr size_t OFF_W     = 4096;                     // 4 x 512*512 bf16 = 2 MB
static constexpr size_t OFF_HT    = OFF_W + 4u * 524288u;     // hnorm_t [4][4096][512] bf16 (aliased w/ Oimg_t)
static constexpr size_t OFF_Q     = OFF_HT + 16777216u;       // Q [16][8][1024][64] bf16
static constexpr size_t OFF_K     = OFF_Q + 16777216u;
static constexpr size_t OFF_V     = OFF_K + 16777216u;        // V^T [16][8][64][1024] bf16
static constexpr size_t OFF_O     = OFF_HT;                   // alias: hnorm_t dead after QKV gemm

__device__ __forceinline__ unsigned short f2bf(float f) {
  unsigned int u = __float_as_uint(f);
  u += 0x7fffu + ((u >> 16) & 1u);
  return (unsigned short)(u >> 16);
}

// ---------------- weight fp32 -> bf16 ----------------
__global__ __launch_bounds__(256) void wconv_k(const float* __restrict__ w0, const float* __restrict__ w1,
                                               const float* __restrict__ w2, const float* __restrict__ w3,
                                               unsigned short* __restrict__ dst) {
  const float* srcs[4] = {w0, w1, w2, w3};
  const float* src = srcs[blockIdx.y];
  unsigned short* d = dst + (size_t)blockIdx.y * 262144u;
  int i = (blockIdx.x * 256 + threadIdx.x) * 4;
  float4 v = *(const float4*)(src + i);
  unsigned int lo = (unsigned int)f2bf(v.x) | ((unsigned int)f2bf(v.y) << 16);
  unsigned int hi = (unsigned int)f2bf(v.z) | ((unsigned int)f2bf(v.w) << 16);
  uint2 pk; pk.x = lo; pk.y = hi;
  *(uint2*)(d + i) = pk;
}

// ---------------- groupnorm stats: 128 blocks = (b,g) ----------------
__global__ __launch_bounds__(256) void gn_stats_k(const float* __restrict__ x, float* __restrict__ stats) {
  int bg = blockIdx.x;
  const float* p = x + (size_t)bg * 65536u;
  int t = threadIdx.x;
  float s = 0.f, ss = 0.f;
  for (int i = t * 4; i < 65536; i += 1024) {
    float4 v = *(const float4*)(p + i);
    s += v.x + v.y + v.z + v.w;
    ss += v.x * v.x + v.y * v.y + v.z * v.z + v.w * v.w;
  }
  for (int m = 1; m <= 32; m <<= 1) { s += __shfl_xor(s, m); ss += __shfl_xor(ss, m); }
  __shared__ float rs[4], rss[4];
  int wv = t >> 6;
  if ((t & 63) == 0) { rs[wv] = s; rss[wv] = ss; }
  __syncthreads();
  if (t == 0) {
    s = rs[0] + rs[1] + rs[2] + rs[3];
    ss = rss[0] + rss[1] + rss[2] + rss[3];
    float mean = s * (1.f / 65536.f);
    float var = ss * (1.f / 65536.f) - mean * mean;
    stats[bg * 2] = mean;
    stats[bg * 2 + 1] = rsqrtf(var + 1e-6f);
  }
}

// ---------------- groupnorm apply + transpose to [b][s][c] bf16 ----------------
__global__ __launch_bounds__(256) void gn_apply_k(const float* __restrict__ x, const float* __restrict__ scale,
                                                  const float* __restrict__ bias, const float* __restrict__ stats,
                                                  unsigned short* __restrict__ ht) {
  __shared__ float tile[64][65];
  int blk = blockIdx.x;
  int b = blk >> 9, cblk = (blk >> 6) & 7, sblk = blk & 63;
  int c0 = cblk * 64, s0 = sblk * 64;
  int t = threadIdx.x;
#pragma unroll
  for (int p = 0; p < 4; ++p) {
    int i = p * 16 + (t >> 4);
    int j = (t & 15) * 4;
    int c = c0 + i;
    float mean = stats[(b * 32 + (c >> 4)) * 2];
    float rstd = stats[(b * 32 + (c >> 4)) * 2 + 1];
    float a = rstd * scale[c];
    float b2 = bias[c] - mean * a;
    float4 v = *(const float4*)(x + ((size_t)(b * 512 + c)) * 4096u + s0 + j);
    tile[i][j + 0] = v.x * a + b2;
    tile[i][j + 1] = v.y * a + b2;
    tile[i][j + 2] = v.z * a + b2;
    tile[i][j + 3] = v.w * a + b2;
  }
  __syncthreads();
#pragma unroll
  for (int p = 0; p < 8; ++p) {
    int jj = p * 8 + (t >> 5);
    int c2 = (t & 31) * 2;
    unsigned int pk = (unsigned int)f2bf(tile[c2][jj]) | ((unsigned int)f2bf(tile[c2 + 1][jj]) << 16);
    *(unsigned int*)(ht + ((size_t)b * 4096u + s0 + jj) * 512u + c0 + c2) = pk;
  }
}

// ---------------- QKV projection GEMM (dbuf + register prefetch) ----------------
// z = proj*4 + b.  proj 0,1 (Q,K): D[s][o] -> Q/K att layout.  proj 2 (V): D[o][s] -> V^T layout.
__global__ __launch_bounds__(256, 2) void qkv_gemm_k(const unsigned short* __restrict__ wbf,
                                                     const unsigned short* __restrict__ ht,
                                                     const float* __restrict__ bq, const float* __restrict__ bk,
                                                     const float* __restrict__ bv,
                                                     unsigned short* __restrict__ Qatt,
                                                     unsigned short* __restrict__ Katt,
                                                     unsigned short* __restrict__ Vt) {
  int proj = blockIdx.z >> 2, b = blockIdx.z & 3;
  const unsigned short* W = wbf + (size_t)proj * 262144u;
  const float* biasp = (proj == 0) ? bq : (proj == 1) ? bk : bv;
  int o0 = blockIdx.x * 128, s0 = blockIdx.y * 128;
  __shared__ unsigned short Wl[2][128 * 72];
  __shared__ unsigned short Xl[2][128 * 72];
  int t = threadIdx.x, lane = t & 63, wv = t >> 6;
  int col_l = lane & 31, half = lane >> 5;
  int qm = (wv >> 1) * 64, qn = (wv & 1) * 64;
  f32x16 acc[2][2];
#pragma unroll
  for (int i = 0; i < 2; i++)
#pragma unroll
    for (int j = 0; j < 2; j++)
#pragma unroll
      for (int r = 0; r < 16; r++) acc[i][j][r] = 0.f;

  const unsigned short* hb = ht + ((size_t)b * 4096u + s0) * 512u;
  int row = t >> 3, ch = (t & 7) * 8;

  uint4 wr[4], xr[4];
#pragma unroll
  for (int p = 0; p < 4; ++p) {
    wr[p] = *(const uint4*)(W + (size_t)(o0 + row + 32 * p) * 512u + ch);
    xr[p] = *(const uint4*)(hb + (size_t)(row + 32 * p) * 512u + ch);
  }

  for (int kb8 = 0; kb8 < 8; ++kb8) {
    int buf = kb8 & 1;
    unsigned short* Wc = Wl[buf];
    unsigned short* Xc = Xl[buf];
#pragma unroll
    for (int p = 0; p < 4; ++p) {
      *(uint4*)(Wc + (row + 32 * p) * 72 + ch) = wr[p];
      *(uint4*)(Xc + (row + 32 * p) * 72 + ch) = xr[p];
    }
    __syncthreads();
    if (kb8 < 7) {
      int kb = (kb8 + 1) * 64;
#pragma unroll
      for (int p = 0; p < 4; ++p) {
        wr[p] = *(const uint4*)(W + (size_t)(o0 + row + 32 * p) * 512u + kb + ch);
        xr[p] = *(const uint4*)(hb + (size_t)(row + 32 * p) * 512u + kb + ch);
      }
    }
    const unsigned short* aT = (proj == 2) ? Wc : Xc;
    const unsigned short* bT = (proj == 2) ? Xc : Wc;
#pragma unroll
    for (int ks = 0; ks < 64; ks += 16) {
      bf16x8 a0 = *(const bf16x8*)(aT + (qm + col_l) * 72 + ks + 8 * half);
      bf16x8 a1 = *(const bf16x8*)(aT + (qm + 32 + col_l) * 72 + ks + 8 * half);
      bf16x8 b0 = *(const bf16x8*)(bT + (qn + col_l) * 72 + ks + 8 * half);
      bf16x8 b1 = *(const bf16x8*)(bT + (qn + 32 + col_l) * 72 + ks + 8 * half);
      acc[0][0] = MFMA32(a0, b0, acc[0][0]);
      acc[0][1] = MFMA32(a0, b1, acc[0][1]);
      acc[1][0] = MFMA32(a1, b0, acc[1][0]);
      acc[1][1] = MFMA32(a1, b1, acc[1][1]);
    }
  }

  if (proj <= 1) {
    unsigned short* dst = (proj == 0) ? Qatt : Katt;
#pragma unroll
    for (int i = 0; i < 2; i++)
#pragma unroll
      for (int j = 0; j < 2; j++) {
        int o = o0 + qn + 32 * j + col_l;
        int head = o >> 6, dd = o & 63;
        float bb = biasp[o];
#pragma unroll
        for (int r = 0; r < 16; r++) {
          int s = s0 + qm + 32 * i + ROWOF(r, half);
          int h = s >> 6, w = s & 63;
          int win = b * 4 + (h >> 5) * 2 + (w >> 5);
          int n = ((h & 31) << 5) | (w & 31);
          dst[(((size_t)(win * 8 + head)) * 1024u + n) * 64u + dd] = f2bf(acc[i][j][r] + bb);
        }
      }
  } else {
#pragma unroll
    for (int i = 0; i < 2; i++)
#pragma unroll
      for (int j = 0; j < 2; j++) {
        int s = s0 + qn + 32 * j + col_l;
        int h = s >> 6, w = s & 63;
        int win = b * 4 + (h >> 5) * 2 + (w >> 5);
        int n = ((h & 31) << 5) | (w & 31);
#pragma unroll
        for (int r = 0; r < 16; r++) {
          int o = o0 + qm + 32 * i + ROWOF(r, half);
          int head = o >> 6, dd = o & 63;
          Vt[(((size_t)(win * 8 + head)) * 64u + dd) * 1024u + n] = f2bf(acc[i][j][r] + biasp[o]);
        }
      }
  }
}

// ---------------- flash attention v5 ----------------
// R4 + double-buffered LDS with register prefetch, ONE barrier per kt.
// Safety: a wave writing buf at iter kt+2 passed barrier(kt+1), which required
// all waves to finish iter-kt compute (the readers of buf).
// XCD swizzle: grid (x = win*8+head [128], y = rb [8]).
__global__ __launch_bounds__(256, 2) void attn_k(const unsigned short* __restrict__ Qatt,
                                                 const unsigned short* __restrict__ Katt,
                                                 const unsigned short* __restrict__ Vt,
                                                 unsigned short* __restrict__ Oimg) {
  int wh_idx = blockIdx.x, rb = blockIdx.y;
  int win = wh_idx >> 3, head = wh_idx & 7;
  int t = threadIdx.x, lane = t & 63, wv = t >> 6;
  int col_l = lane & 31, half = lane >> 5;
  __shared__ unsigned short Kl[2][128 * 72];  // K tile [n=128][d=64] pitch 72
  __shared__ unsigned short Vl[2][64 * 136];  // V^T tile [d=64][n=128] pitch 136
  const size_t wh = (size_t)wh_idx;
  const unsigned short* Qb = Qatt + wh * 65536u;
  const unsigned short* Kb = Katt + wh * 65536u;
  const unsigned short* Vb = Vt + wh * 65536u;

  int krow = t >> 3, kch = (t & 7) * 8;
  int vrow = t >> 4, vch = (t & 15) * 8;

  uint4 kr[4], vr[4];
#pragma unroll
  for (int p = 0; p < 4; ++p) {
    kr[p] = *(const uint4*)(Kb + (size_t)(krow + 32 * p) * 64u + kch);
    vr[p] = *(const uint4*)(Vb + (size_t)(vrow + 16 * p) * 1024u + vch);
  }

  int qrow = rb * 128 + wv * 32 + col_l;
  bf16x8 qf[4];
#pragma unroll
  for (int kk = 0; kk < 4; kk++) qf[kk] = *(const bf16x8*)(Qb + (size_t)qrow * 64u + kk * 16 + 8 * half);

  f32x16 oacc[2];
#pragma unroll
  for (int j = 0; j < 2; j++)
#pragma unroll
    for (int r = 0; r < 16; r++) oacc[j][r] = 0.f;
  float lsum = 0.f;

  const float SC = 0.125f * 1.44269504f;  // scale * log2(e); scores small -> fixed-max softmax

  for (int kt = 0; kt < 8; ++kt) {
    unsigned short* Kc = Kl[kt & 1];
    unsigned short* Vc = Vl[kt & 1];
#pragma unroll
    for (int p = 0; p < 4; ++p) {
      *(uint4*)(Kc + (krow + 32 * p) * 72 + kch) = kr[p];
      *(uint4*)(Vc + (vrow + 16 * p) * 136 + vch) = vr[p];
    }
    __syncthreads();
    if (kt < 7) {
      int nk = (kt + 1) * 128;
#pragma unroll
      for (int p = 0; p < 4; ++p) {
        kr[p] = *(const uint4*)(Kb + (size_t)(nk + krow + 32 * p) * 64u + kch);
        vr[p] = *(const uint4*)(Vb + (size_t)(vrow + 16 * p) * 1024u + nk + vch);
      }
    }

    // S^T tile: [128 keys x 32 q], A = K rows, B = Q rows (as cols)
    f32x16 sacc[4];
#pragma unroll
    for (int jb = 0; jb < 4; jb++)
#pragma unroll
      for (int r = 0; r < 16; r++) sacc[jb][r] = 0.f;
#pragma unroll
    for (int jb = 0; jb < 4; jb++) {
#pragma unroll
      for (int kk = 0; kk < 4; kk++) {
        bf16x8 af = *(const bf16x8*)(Kc + (jb * 32 + col_l) * 72 + kk * 16 + 8 * half);
        sacc[jb] = MFMA32(af, qf[kk], sacc[jb]);
      }
    }

    // per 32-key block: exp -> pack bf16 (trunc) -> half-wave exchange -> PV MFMA
#pragma unroll
    for (int jb = 0; jb < 4; jb++) {
      float p[16];
#pragma unroll
      for (int r = 0; r < 16; r++) p[r] = __builtin_amdgcn_exp2f(sacc[jb][r] * SC);
      float ps = ((p[0] + p[1]) + (p[2] + p[3])) + ((p[4] + p[5]) + (p[6] + p[7]));
      ps += ((p[8] + p[9]) + (p[10] + p[11])) + ((p[12] + p[13]) + (p[14] + p[15]));
      lsum += ps;
      unsigned int pk[8];
#pragma unroll
      for (int j = 0; j < 8; j++)
        pk[j] = __builtin_amdgcn_perm(__float_as_uint(p[2 * j + 1]), __float_as_uint(p[2 * j]), 0x07060302u);
      // exchange with lane^32 to build A-operand fragments
      unsigned int rA = __shfl_xor((int)(half ? pk[0] : pk[2]), 32);
      unsigned int rB = __shfl_xor((int)(half ? pk[1] : pk[3]), 32);
      unsigned int rC = __shfl_xor((int)(half ? pk[4] : pk[6]), 32);
      unsigned int rD = __shfl_xor((int)(half ? pk[5] : pk[7]), 32);
      u32x4 f0, f1;
      f0[0] = half ? rA : pk[0];
      f0[1] = half ? rB : pk[1];
      f0[2] = half ? pk[2] : rA;
      f0[3] = half ? pk[3] : rB;
      f1[0] = half ? rC : pk[4];
      f1[1] = half ? rD : pk[5];
      f1[2] = half ? pk[6] : rC;
      f1[3] = half ? pk[7] : rD;
      bf16x8 pa0 = __builtin_bit_cast(bf16x8, f0);
      bf16x8 pa1 = __builtin_bit_cast(bf16x8, f1);
#pragma unroll
      for (int dblk = 0; dblk < 2; dblk++) {
        bf16x8 v0 = *(const bf16x8*)(Vc + (dblk * 32 + col_l) * 136 + (jb * 2 + 0) * 16 + 8 * half);
        bf16x8 v1 = *(const bf16x8*)(Vc + (dblk * 32 + col_l) * 136 + (jb * 2 + 1) * 16 + 8 * half);
        oacc[dblk] = MFMA32(pa0, v0, oacc[dblk]);
        oacc[dblk] = MFMA32(pa1, v1, oacc[dblk]);
      }
    }
  }

  float l = lsum + __shfl_xor(lsum, 32);
  float inv = 1.f / l;

  int b = win >> 2, whn = (win >> 1) & 1, wwn = win & 1;
#pragma unroll
  for (int r = 0; r < 16; r++) {
    int qr = ROWOF(r, half);
    float invr = __shfl(inv, qr);
    int ntok = rb * 128 + wv * 32 + qr;
    int h = whn * 32 + (ntok >> 5), w = wwn * 32 + (ntok & 31);
    int s = h * 64 + w;
    size_t rowbase = ((size_t)b * 4096u + s) * 512u + head * 64;
    Oimg[rowbase + col_l] = f2bf(oacc[0][r] * invr);
    Oimg[rowbase + 32 + col_l] = f2bf(oacc[1][r] * invr);
  }
}

// ---------------- output projection + residual (dbuf + prefetch): D[o][s], grid (4,32,4) ----------------
__global__ __launch_bounds__(256, 2) void out_gemm_k(const unsigned short* __restrict__ wo_bf,
                                                     const unsigned short* __restrict__ Oimg,
                                                     const float* __restrict__ bo, const float* __restrict__ x,
                                                     float* __restrict__ out) {
  int b = blockIdx.z;
  int o0 = blockIdx.x * 128, s0 = blockIdx.y * 128;
  __shared__ unsigned short Wl[2][128 * 72];
  __shared__ unsigned short Xl[2][128 * 72];
  int t = threadIdx.x, lane = t & 63, wv = t >> 6;
  int col_l = lane & 31, half = lane >> 5;
  int qm = (wv >> 1) * 64, qn = (wv & 1) * 64;
  f32x16 acc[2][2];
#pragma unroll
  for (int i = 0; i < 2; i++)
#pragma unroll
    for (int j = 0; j < 2; j++)
#pragma unroll
      for (int r = 0; r < 16; r++) acc[i][j][r] = 0.f;

  const unsigned short* ob = Oimg + ((size_t)b * 4096u + s0) * 512u;
  int row = t >> 3, ch = (t & 7) * 8;

  uint4 wr[4], xr[4];
#pragma unroll
  for (int p = 0; p < 4; ++p) {
    wr[p] = *(const uint4*)(wo_bf + (size_t)(o0 + row + 32 * p) * 512u + ch);
    xr[p] = *(const uint4*)(ob + (size_t)(row + 32 * p) * 512u + ch);
  }

  for (int kb8 = 0; kb8 < 8; ++kb8) {
    int buf = kb8 & 1;
    unsigned short* Wc = Wl[buf];
    unsigned short* Xc = Xl[buf];
#pragma unroll
    for (int p = 0; p < 4; ++p) {
      *(uint4*)(Wc + (row + 32 * p) * 72 + ch) = wr[p];
      *(uint4*)(Xc + (row + 32 * p) * 72 + ch) = xr[p];
    }
    __syncthreads();
    if (kb8 < 7) {
      int kb = (kb8 + 1) * 64;
#pragma unroll
      for (int p = 0; p < 4; ++p) {
        wr[p] = *(const uint4*)(wo_bf + (size_t)(o0 + row + 32 * p) * 512u + kb + ch);
        xr[p] = *(const uint4*)(ob + (size_t)(row + 32 * p) * 512u + kb + ch);
      }
    }
#pragma unroll
    for (int ks = 0; ks < 64; ks += 16) {
      bf16x8 a0 = *(const bf16x8*)(Wc + (qm + col_l) * 72 + ks + 8 * half);
      bf16x8 a1 = *(const bf16x8*)(Wc + (qm + 32 + col_l) * 72 + ks + 8 * half);
      bf16x8 b0 = *(const bf16x8*)(Xc + (qn + col_l) * 72 + ks + 8 * half);
      bf16x8 b1 = *(const bf16x8*)(Xc + (qn + 32 + col_l) * 72 + ks + 8 * half);
      acc[0][0] = MFMA32(a0, b0, acc[0][0]);
      acc[0][1] = MFMA32(a0, b1, acc[0][1]);
      acc[1][0] = MFMA32(a1, b0, acc[1][0]);
      acc[1][1] = MFMA32(a1, b1, acc[1][1]);
    }
  }
#pragma unroll
  for (int i = 0; i < 2; i++)
#pragma unroll
    for (int j = 0; j < 2; j++) {
      int s = s0 + qn + 32 * j + col_l;
#pragma unroll
      for (int r = 0; r < 16; r++) {
        int o = o0 + qm + 32 * i + ROWOF(r, half);
        size_t idx = ((size_t)b * 512u + o) * 4096u + s;
        out[idx] = x[idx] + acc[i][j][r] + bo[o];
      }
    }
}

extern "C" void kernel_launch(void* const* d_in, const int* in_sizes, int n_in,
                              void* d_out, int out_size, void* d_ws, size_t ws_size,
                              hipStream_t stream) {
  const float* x = (const float*)d_in[0];
  const float* nsc = (const float*)d_in[1];
  const float* nbi = (const float*)d_in[2];
  const float* wq = (const float*)d_in[3];
  const float* bq = (const float*)d_in[4];
  const float* wk = (const float*)d_in[5];
  const float* bk = (const float*)d_in[6];
  const float* wvp = (const float*)d_in[7];
  const float* bv = (const float*)d_in[8];
  const float* wo = (const float*)d_in[9];
  const float* bo = (const float*)d_in[10];
  float* out = (float*)d_out;
  char* ws = (char*)d_ws;

  float* stats = (float*)(ws + OFF_STATS);
  unsigned short* wbf = (unsigned short*)(ws + OFF_W);
  unsigned short* ht = (unsigned short*)(ws + OFF_HT);
  unsigned short* Qatt = (unsigned short*)(ws + OFF_Q);
  unsigned short* Katt = (unsigned short*)(ws + OFF_K);
  unsigned short* Vt = (unsigned short*)(ws + OFF_V);
  unsigned short* Oimg = (unsigned short*)(ws + OFF_O);

  wconv_k<<<dim3(256, 4), 256, 0, stream>>>(wq, wk, wvp, wo, wbf);
  gn_stats_k<<<128, 256, 0, stream>>>(x, stats);
  gn_apply_k<<<2048, 256, 0, stream>>>(x, nsc, nbi, stats, ht);
  qkv_gemm_k<<<dim3(4, 32, 12), 256, 0, stream>>>(wbf, ht, bq, bk, bv, Qatt, Katt, Vt);
  attn_k<<<dim3(128, 8), 256, 0, stream>>>(Qatt, Katt, Vt, Oimg);
  out_gemm_k<<<dim3(4, 32, 4), 256, 0, stream>>>(wbf + 3u * 262144u, Oimg, bo, x, out);
}

// Round 6
// 271.480 us; speedup vs baseline: 1.1975x; 1.1975x over previous
//
#include <hip/hip_runtime.h>
#include <math.h>

typedef __bf16 bf16_t;
typedef bf16_t bf16x8 __attribute__((ext_vector_type(8)));
typedef float f32x16 __attribute__((ext_vector_type(16)));
typedef unsigned int u32x4 __attribute__((ext_vector_type(4)));

#define MFMA32(a, b, c) __builtin_amdgcn_mfma_f32_32x32x16_bf16(a, b, c, 0, 0, 0)
#define ROWOF(r, h) (((r) & 3) + 8 * ((r) >> 2) + 4 * (h))

// ---- problem constants ----
// B=4, C=512, H=W=64, WS=32, NH=8 heads, DH=64, GROUPS=32 (16 ch/group)
// windows: 16 total (b*4 + wh*2 + ww), tokens n=1024 per window

// ---- workspace layout (bytes) ----
static constexpr size_t OFF_STATS = 0;                        // 128*2 f32
static constexpr size_t OFF_W     = 4096;                     // 4 x 512*512 bf16 = 2 MB
static constexpr size_t OFF_HT    = OFF_W + 4u * 524288u;     // hnorm_t [4][4096][512] bf16 (aliased w/ Oimg_t)
static constexpr size_t OFF_Q     = OFF_HT + 16777216u;       // Q [16][8][1024][64] bf16
static constexpr size_t OFF_K     = OFF_Q + 16777216u;
static constexpr size_t OFF_V     = OFF_K + 16777216u;        // V^T [16][8][64][1024] bf16
static constexpr size_t OFF_O     = OFF_HT;                   // alias: hnorm_t dead after QKV gemm

__device__ __forceinline__ unsigned short f2bf(float f) {
  unsigned int u = __float_as_uint(f);
  u += 0x7fffu + ((u >> 16) & 1u);
  return (unsigned short)(u >> 16);
}

// async global->LDS, 16B per lane; LDS dest = wave-uniform base + lane*16
__device__ __forceinline__ void gl_lds16(const unsigned short* g, unsigned short* lds_base) {
  __builtin_amdgcn_global_load_lds(
      (const __attribute__((address_space(1))) unsigned int*)g,
      (__attribute__((address_space(3))) unsigned int*)(unsigned int)(unsigned long long)lds_base,
      16, 0, 0);
}

// ---------------- weight fp32 -> bf16 ----------------
__global__ __launch_bounds__(256) void wconv_k(const float* __restrict__ w0, const float* __restrict__ w1,
                                               const float* __restrict__ w2, const float* __restrict__ w3,
                                               unsigned short* __restrict__ dst) {
  const float* srcs[4] = {w0, w1, w2, w3};
  const float* src = srcs[blockIdx.y];
  unsigned short* d = dst + (size_t)blockIdx.y * 262144u;
  int i = (blockIdx.x * 256 + threadIdx.x) * 4;
  float4 v = *(const float4*)(src + i);
  unsigned int lo = (unsigned int)f2bf(v.x) | ((unsigned int)f2bf(v.y) << 16);
  unsigned int hi = (unsigned int)f2bf(v.z) | ((unsigned int)f2bf(v.w) << 16);
  uint2 pk; pk.x = lo; pk.y = hi;
  *(uint2*)(d + i) = pk;
}

// ---------------- groupnorm stats: 128 blocks = (b,g) ----------------
__global__ __launch_bounds__(256) void gn_stats_k(const float* __restrict__ x, float* __restrict__ stats) {
  int bg = blockIdx.x;
  const float* p = x + (size_t)bg * 65536u;
  int t = threadIdx.x;
  float s = 0.f, ss = 0.f;
  for (int i = t * 4; i < 65536; i += 1024) {
    float4 v = *(const float4*)(p + i);
    s += v.x + v.y + v.z + v.w;
    ss += v.x * v.x + v.y * v.y + v.z * v.z + v.w * v.w;
  }
  for (int m = 1; m <= 32; m <<= 1) { s += __shfl_xor(s, m); ss += __shfl_xor(ss, m); }
  __shared__ float rs[4], rss[4];
  int wv = t >> 6;
  if ((t & 63) == 0) { rs[wv] = s; rss[wv] = ss; }
  __syncthreads();
  if (t == 0) {
    s = rs[0] + rs[1] + rs[2] + rs[3];
    ss = rss[0] + rss[1] + rss[2] + rss[3];
    float mean = s * (1.f / 65536.f);
    float var = ss * (1.f / 65536.f) - mean * mean;
    stats[bg * 2] = mean;
    stats[bg * 2 + 1] = rsqrtf(var + 1e-6f);
  }
}

// ---------------- groupnorm apply + transpose to [b][s][c] bf16 ----------------
__global__ __launch_bounds__(256) void gn_apply_k(const float* __restrict__ x, const float* __restrict__ scale,
                                                  const float* __restrict__ bias, const float* __restrict__ stats,
                                                  unsigned short* __restrict__ ht) {
  __shared__ float tile[64][65];
  int blk = blockIdx.x;
  int b = blk >> 9, cblk = (blk >> 6) & 7, sblk = blk & 63;
  int c0 = cblk * 64, s0 = sblk * 64;
  int t = threadIdx.x;
#pragma unroll
  for (int p = 0; p < 4; ++p) {
    int i = p * 16 + (t >> 4);
    int j = (t & 15) * 4;
    int c = c0 + i;
    float mean = stats[(b * 32 + (c >> 4)) * 2];
    float rstd = stats[(b * 32 + (c >> 4)) * 2 + 1];
    float a = rstd * scale[c];
    float b2 = bias[c] - mean * a;
    float4 v = *(const float4*)(x + ((size_t)(b * 512 + c)) * 4096u + s0 + j);
    tile[i][j + 0] = v.x * a + b2;
    tile[i][j + 1] = v.y * a + b2;
    tile[i][j + 2] = v.z * a + b2;
    tile[i][j + 3] = v.w * a + b2;
  }
  __syncthreads();
#pragma unroll
  for (int p = 0; p < 8; ++p) {
    int jj = p * 8 + (t >> 5);
    int c2 = (t & 31) * 2;
    unsigned int pk = (unsigned int)f2bf(tile[c2][jj]) | ((unsigned int)f2bf(tile[c2 + 1][jj]) << 16);
    *(unsigned int*)(ht + ((size_t)b * 4096u + s0 + jj) * 512u + c0 + c2) = pk;
  }
}

// ---------------- QKV projection GEMM (R4 single-buffer form) ----------------
// z = proj*4 + b.  proj 0,1 (Q,K): D[s][o] -> Q/K att layout.  proj 2 (V): D[o][s] -> V^T layout.
__global__ __launch_bounds__(256, 2) void qkv_gemm_k(const unsigned short* __restrict__ wbf,
                                                     const unsigned short* __restrict__ ht,
                                                     const float* __restrict__ bq, const float* __restrict__ bk,
                                                     const float* __restrict__ bv,
                                                     unsigned short* __restrict__ Qatt,
                                                     unsigned short* __restrict__ Katt,
                                                     unsigned short* __restrict__ Vt) {
  int proj = blockIdx.z >> 2, b = blockIdx.z & 3;
  const unsigned short* W = wbf + (size_t)proj * 262144u;
  const float* biasp = (proj == 0) ? bq : (proj == 1) ? bk : bv;
  int o0 = blockIdx.x * 128, s0 = blockIdx.y * 128;
  __shared__ unsigned short Wl[128 * 72];
  __shared__ unsigned short Xl[128 * 72];
  int t = threadIdx.x, lane = t & 63, wv = t >> 6;
  int col_l = lane & 31, half = lane >> 5;
  int qm = (wv >> 1) * 64, qn = (wv & 1) * 64;
  f32x16 acc[2][2];
#pragma unroll
  for (int i = 0; i < 2; i++)
#pragma unroll
    for (int j = 0; j < 2; j++)
#pragma unroll
      for (int r = 0; r < 16; r++) acc[i][j][r] = 0.f;

  const unsigned short* hb = ht + ((size_t)b * 4096u + s0) * 512u;
  for (int kb = 0; kb < 512; kb += 64) {
    __syncthreads();
    {
      int row = t >> 3, ch = (t & 7) * 8;
#pragma unroll
      for (int p = 0; p < 4; ++p, row += 32) {
        *(uint4*)(Wl + row * 72 + ch) = *(const uint4*)(W + (size_t)(o0 + row) * 512u + kb + ch);
        *(uint4*)(Xl + row * 72 + ch) = *(const uint4*)(hb + (size_t)row * 512u + kb + ch);
      }
    }
    __syncthreads();
    const unsigned short* aT = (proj == 2) ? Wl : Xl;
    const unsigned short* bT = (proj == 2) ? Xl : Wl;
#pragma unroll
    for (int ks = 0; ks < 64; ks += 16) {
      bf16x8 a0 = *(const bf16x8*)(aT + (qm + col_l) * 72 + ks + 8 * half);
      bf16x8 a1 = *(const bf16x8*)(aT + (qm + 32 + col_l) * 72 + ks + 8 * half);
      bf16x8 b0 = *(const bf16x8*)(bT + (qn + col_l) * 72 + ks + 8 * half);
      bf16x8 b1 = *(const bf16x8*)(bT + (qn + 32 + col_l) * 72 + ks + 8 * half);
      acc[0][0] = MFMA32(a0, b0, acc[0][0]);
      acc[0][1] = MFMA32(a0, b1, acc[0][1]);
      acc[1][0] = MFMA32(a1, b0, acc[1][0]);
      acc[1][1] = MFMA32(a1, b1, acc[1][1]);
    }
  }

  if (proj <= 1) {
    unsigned short* dst = (proj == 0) ? Qatt : Katt;
#pragma unroll
    for (int i = 0; i < 2; i++)
#pragma unroll
      for (int j = 0; j < 2; j++) {
        int o = o0 + qn + 32 * j + col_l;
        int head = o >> 6, dd = o & 63;
        float bb = biasp[o];
#pragma unroll
        for (int r = 0; r < 16; r++) {
          int s = s0 + qm + 32 * i + ROWOF(r, half);
          int h = s >> 6, w = s & 63;
          int win = b * 4 + (h >> 5) * 2 + (w >> 5);
          int n = ((h & 31) << 5) | (w & 31);
          dst[(((size_t)(win * 8 + head)) * 1024u + n) * 64u + dd] = f2bf(acc[i][j][r] + bb);
        }
      }
  } else {
#pragma unroll
    for (int i = 0; i < 2; i++)
#pragma unroll
      for (int j = 0; j < 2; j++) {
        int s = s0 + qn + 32 * j + col_l;
        int h = s >> 6, w = s & 63;
        int win = b * 4 + (h >> 5) * 2 + (w >> 5);
        int n = ((h & 31) << 5) | (w & 31);
#pragma unroll
        for (int r = 0; r < 16; r++) {
          int o = o0 + qm + 32 * i + ROWOF(r, half);
          int head = o >> 6, dd = o & 63;
          Vt[(((size_t)(win * 8 + head)) * 64u + dd) * 1024u + n] = f2bf(acc[i][j][r] + biasp[o]);
        }
      }
  }
}

// ---------------- flash attention v6: async global_load_lds + dbuf LDS ----------------
// grid (x = win*8+head [128], y = rb [8]), 256 thr. XCD swizzle as R4.
// LDS tiles UNPADDED with 16B XOR swizzle (K: chunk^=(r&7), V: chunk^=(r&15));
// quarter-wave phases then hit 8 bank-groups x2 = 2-way (free).
// One barrier + one vmcnt(0) per kt; kt+1 loads issued right after barrier.
__global__ __launch_bounds__(256, 2) void attn_k(const unsigned short* __restrict__ Qatt,
                                                 const unsigned short* __restrict__ Katt,
                                                 const unsigned short* __restrict__ Vt,
                                                 unsigned short* __restrict__ Oimg) {
  int wh_idx = blockIdx.x, rb = blockIdx.y;
  int win = wh_idx >> 3, head = wh_idx & 7;
  int t = threadIdx.x, lane = t & 63, wv = t >> 6;
  int col_l = lane & 31, half = lane >> 5;
  __shared__ unsigned short Kl[2][128 * 64];  // K tile [n=128][d=64], 16B-xor-swizzled rows
  __shared__ unsigned short Vl[2][64 * 128];  // V^T tile [d=64][n=128], 16B-xor-swizzled rows
  const size_t wh = (size_t)wh_idx;
  const unsigned short* Qb = Qatt + wh * 65536u;
  const unsigned short* Kb = Katt + wh * 65536u;
  const unsigned short* Vb = Vt + wh * 65536u;

  // staging geometry: slot s = wv*256 + i*64 + lane (16B slots)
  // K: r = s>>3, pcb = s&7, src chunk = pcb ^ (r&7)
  // V: r = s>>4, pch = s&15, src chunk = pch ^ (r&15)
  int ks_r[4], ks_off[4], vs_r[4], vs_off[4];
#pragma unroll
  for (int i = 0; i < 4; ++i) {
    int s = wv * 256 + i * 64 + lane;
    ks_r[i] = s >> 3;
    ks_off[i] = ((s & 7) ^ (ks_r[i] & 7)) * 8;
    vs_r[i] = s >> 4;
    vs_off[i] = ((s & 15) ^ (vs_r[i] & 15)) * 8;
  }

  // issue kt=0 tile loads
#pragma unroll
  for (int i = 0; i < 4; ++i) {
    gl_lds16(Kb + (size_t)ks_r[i] * 64u + ks_off[i], &Kl[0][0] + wv * 2048 + i * 512);
    gl_lds16(Vb + (size_t)vs_r[i] * 1024u + vs_off[i], &Vl[0][0] + wv * 2048 + i * 512);
  }

  int qrow = rb * 128 + wv * 32 + col_l;
  bf16x8 qf[4];
#pragma unroll
  for (int kk = 0; kk < 4; kk++) qf[kk] = *(const bf16x8*)(Qb + (size_t)qrow * 64u + kk * 16 + 8 * half);

  f32x16 oacc[2];
#pragma unroll
  for (int j = 0; j < 2; j++)
#pragma unroll
    for (int r = 0; r < 16; r++) oacc[j][r] = 0.f;
  float lsum = 0.f;

  const float SC = 0.125f * 1.44269504f;  // scale * log2(e); scores small -> fixed-max softmax
  const int kx = col_l & 7;               // K-row xor key (row = jb*32+col_l, 32%8==0)
  const int vx = col_l & 15;              // V-row xor key

  for (int kt = 0; kt < 8; ++kt) {
    const unsigned short* Kc = Kl[kt & 1];
    const unsigned short* Vc = Vl[kt & 1];
    __builtin_amdgcn_s_waitcnt(0x0F70);  // vmcnt(0): this wave's kt-tile DMA done
    __syncthreads();                     // all waves' DMA done; prev compute done
    if (kt < 7) {
      unsigned short* Kn = &Kl[(kt + 1) & 1][0];
      unsigned short* Vn = &Vl[(kt + 1) & 1][0];
      int nk = (kt + 1) * 128;
#pragma unroll
      for (int i = 0; i < 4; ++i) {
        gl_lds16(Kb + (size_t)(nk + ks_r[i]) * 64u + ks_off[i], Kn + wv * 2048 + i * 512);
        gl_lds16(Vb + (size_t)vs_r[i] * 1024u + nk + vs_off[i], Vn + wv * 2048 + i * 512);
      }
    }

    // S^T tile: [128 keys x 32 q], A = K rows, B = Q rows (as cols)
    f32x16 sacc[4];
#pragma unroll
    for (int jb = 0; jb < 4; jb++)
#pragma unroll
      for (int r = 0; r < 16; r++) sacc[jb][r] = 0.f;
#pragma unroll
    for (int jb = 0; jb < 4; jb++) {
      const unsigned short* Krow = Kc + (jb * 32 + col_l) * 64;
#pragma unroll
      for (int kk = 0; kk < 4; kk++) {
        bf16x8 af = *(const bf16x8*)(Krow + (((kk * 2 + half) ^ kx) * 8));
        sacc[jb] = MFMA32(af, qf[kk], sacc[jb]);
      }
    }

    // per 32-key block: exp -> pack bf16 (trunc) -> half-wave exchange -> PV MFMA
#pragma unroll
    for (int jb = 0; jb < 4; jb++) {
      float p[16];
#pragma unroll
      for (int r = 0; r < 16; r++) p[r] = __builtin_amdgcn_exp2f(sacc[jb][r] * SC);
      float ps = ((p[0] + p[1]) + (p[2] + p[3])) + ((p[4] + p[5]) + (p[6] + p[7]));
      ps += ((p[8] + p[9]) + (p[10] + p[11])) + ((p[12] + p[13]) + (p[14] + p[15]));
      lsum += ps;
      unsigned int pk[8];
#pragma unroll
      for (int j = 0; j < 8; j++)
        pk[j] = __builtin_amdgcn_perm(__float_as_uint(p[2 * j + 1]), __float_as_uint(p[2 * j]), 0x07060302u);
      // exchange with lane^32 to build A-operand fragments
      unsigned int rA = __shfl_xor((int)(half ? pk[0] : pk[2]), 32);
      unsigned int rB = __shfl_xor((int)(half ? pk[1] : pk[3]), 32);
      unsigned int rC = __shfl_xor((int)(half ? pk[4] : pk[6]), 32);
      unsigned int rD = __shfl_xor((int)(half ? pk[5] : pk[7]), 32);
      u32x4 f0, f1;
      f0[0] = half ? rA : pk[0];
      f0[1] = half ? rB : pk[1];
      f0[2] = half ? pk[2] : rA;
      f0[3] = half ? pk[3] : rB;
      f1[0] = half ? rC : pk[4];
      f1[1] = half ? rD : pk[5];
      f1[2] = half ? pk[6] : rC;
      f1[3] = half ? pk[7] : rD;
      bf16x8 pa0 = __builtin_bit_cast(bf16x8, f0);
      bf16x8 pa1 = __builtin_bit_cast(bf16x8, f1);
#pragma unroll
      for (int dblk = 0; dblk < 2; dblk++) {
        const unsigned short* Vrow = Vc + (dblk * 32 + col_l) * 128;
        bf16x8 v0 = *(const bf16x8*)(Vrow + (((jb * 4 + half) ^ vx) * 8));
        bf16x8 v1 = *(const bf16x8*)(Vrow + (((jb * 4 + 2 + half) ^ vx) * 8));
        oacc[dblk] = MFMA32(pa0, v0, oacc[dblk]);
        oacc[dblk] = MFMA32(pa1, v1, oacc[dblk]);
      }
    }
  }

  float l = lsum + __shfl_xor(lsum, 32);
  float inv = 1.f / l;

  int b = win >> 2, whn = (win >> 1) & 1, wwn = win & 1;
#pragma unroll
  for (int r = 0; r < 16; r++) {
    int qr = ROWOF(r, half);
    float invr = __shfl(inv, qr);
    int ntok = rb * 128 + wv * 32 + qr;
    int h = whn * 32 + (ntok >> 5), w = wwn * 32 + (ntok & 31);
    int s = h * 64 + w;
    size_t rowbase = ((size_t)b * 4096u + s) * 512u + head * 64;
    Oimg[rowbase + col_l] = f2bf(oacc[0][r] * invr);
    Oimg[rowbase + 32 + col_l] = f2bf(oacc[1][r] * invr);
  }
}

// ---------------- output projection + residual (R4 single-buffer form): D[o][s], grid (4,32,4) ----------------
__global__ __launch_bounds__(256, 2) void out_gemm_k(const unsigned short* __restrict__ wo_bf,
                                                     const unsigned short* __restrict__ Oimg,
                                                     const float* __restrict__ bo, const float* __restrict__ x,
                                                     float* __restrict__ out) {
  int b = blockIdx.z;
  int o0 = blockIdx.x * 128, s0 = blockIdx.y * 128;
  __shared__ unsigned short Wl[128 * 72];
  __shared__ unsigned short Xl[128 * 72];
  int t = threadIdx.x, lane = t & 63, wv = t >> 6;
  int col_l = lane & 31, half = lane >> 5;
  int qm = (wv >> 1) * 64, qn = (wv & 1) * 64;
  f32x16 acc[2][2];
#pragma unroll
  for (int i = 0; i < 2; i++)
#pragma unroll
    for (int j = 0; j < 2; j++)
#pragma unroll
      for (int r = 0; r < 16; r++) acc[i][j][r] = 0.f;

  const unsigned short* ob = Oimg + ((size_t)b * 4096u + s0) * 512u;
  for (int kb = 0; kb < 512; kb += 64) {
    __syncthreads();
    {
      int row = t >> 3, ch = (t & 7) * 8;
#pragma unroll
      for (int p = 0; p < 4; ++p, row += 32) {
        *(uint4*)(Wl + row * 72 + ch) = *(const uint4*)(wo_bf + (size_t)(o0 + row) * 512u + kb + ch);
        *(uint4*)(Xl + row * 72 + ch) = *(const uint4*)(ob + (size_t)row * 512u + kb + ch);
      }
    }
    __syncthreads();
#pragma unroll
    for (int ks = 0; ks < 64; ks += 16) {
      bf16x8 a0 = *(const bf16x8*)(Wl + (qm + col_l) * 72 + ks + 8 * half);
      bf16x8 a1 = *(const bf16x8*)(Wl + (qm + 32 + col_l) * 72 + ks + 8 * half);
      bf16x8 b0 = *(const bf16x8*)(Xl + (qn + col_l) * 72 + ks + 8 * half);
      bf16x8 b1 = *(const bf16x8*)(Xl + (qn + 32 + col_l) * 72 + ks + 8 * half);
      acc[0][0] = MFMA32(a0, b0, acc[0][0]);
      acc[0][1] = MFMA32(a0, b1, acc[0][1]);
      acc[1][0] = MFMA32(a1, b0, acc[1][0]);
      acc[1][1] = MFMA32(a1, b1, acc[1][1]);
    }
  }
#pragma unroll
  for (int i = 0; i < 2; i++)
#pragma unroll
    for (int j = 0; j < 2; j++) {
      int s = s0 + qn + 32 * j + col_l;
#pragma unroll
      for (int r = 0; r < 16; r++) {
        int o = o0 + qm + 32 * i + ROWOF(r, half);
        size_t idx = ((size_t)b * 512u + o) * 4096u + s;
        out[idx] = x[idx] + acc[i][j][r] + bo[o];
      }
    }
}

extern "C" void kernel_launch(void* const* d_in, const int* in_sizes, int n_in,
                              void* d_out, int out_size, void* d_ws, size_t ws_size,
                              hipStream_t stream) {
  const float* x = (const float*)d_in[0];
  const float* nsc = (const float*)d_in[1];
  const float* nbi = (const float*)d_in[2];
  const float* wq = (const float*)d_in[3];
  const float* bq = (const float*)d_in[4];
  const float* wk = (const float*)d_in[5];
  const float* bk = (const float*)d_in[6];
  const float* wvp = (const float*)d_in[7];
  const float* bv = (const float*)d_in[8];
  const float* wo = (const float*)d_in[9];
  const float* bo = (const float*)d_in[10];
  float* out = (float*)d_out;
  char* ws = (char*)d_ws;

  float* stats = (float*)(ws + OFF_STATS);
  unsigned short* wbf = (unsigned short*)(ws + OFF_W);
  unsigned short* ht = (unsigned short*)(ws + OFF_HT);
  unsigned short* Qatt = (unsigned short*)(ws + OFF_Q);
  unsigned short* Katt = (unsigned short*)(ws + OFF_K);
  unsigned short* Vt = (unsigned short*)(ws + OFF_V);
  unsigned short* Oimg = (unsigned short*)(ws + OFF_O);

  wconv_k<<<dim3(256, 4), 256, 0, stream>>>(wq, wk, wvp, wo, wbf);
  gn_stats_k<<<128, 256, 0, stream>>>(x, stats);
  gn_apply_k<<<2048, 256, 0, stream>>>(x, nsc, nbi, stats, ht);
  qkv_gemm_k<<<dim3(4, 32, 12), 256, 0, stream>>>(wbf, ht, bq, bk, bv, Qatt, Katt, Vt);
  attn_k<<<dim3(128, 8), 256, 0, stream>>>(Qatt, Katt, Vt, Oimg);
  out_gemm_k<<<dim3(4, 32, 4), 256, 0, stream>>>(wbf + 3u * 262144u, Oimg, bo, x, out);
}

// Round 7
// 263.542 us; speedup vs baseline: 1.2336x; 1.0301x over previous
//
#include <hip/hip_runtime.h>
#include <math.h>

typedef __bf16 bf16_t;
typedef bf16_t bf16x8 __attribute__((ext_vector_type(8)));
typedef float f32x16 __attribute__((ext_vector_type(16)));
typedef unsigned int u32x4 __attribute__((ext_vector_type(4)));

#define MFMA32(a, b, c) __builtin_amdgcn_mfma_f32_32x32x16_bf16(a, b, c, 0, 0, 0)
#define ROWOF(r, h) (((r) & 3) + 8 * ((r) >> 2) + 4 * (h))

// ---- problem constants ----
// B=4, C=512, H=W=64, WS=32, NH=8 heads, DH=64, GROUPS=32 (16 ch/group)
// windows: 16 total (b*4 + wh*2 + ww), tokens n=1024 per window

// ---- workspace layout (bytes) ----
static constexpr size_t OFF_STATS = 0;                        // 128*2 f32
static constexpr size_t OFF_W     = 4096;                     // 4 x 512*512 bf16 = 2 MB
static constexpr size_t OFF_HT    = OFF_W + 4u * 524288u;     // hnorm_t [4][4096][512] bf16 (aliased w/ Oimg_t)
static constexpr size_t OFF_Q     = OFF_HT + 16777216u;       // Q [16][8][1024][64] bf16 (pre-scaled by 0.125*log2e)
static constexpr size_t OFF_K     = OFF_Q + 16777216u;
static constexpr size_t OFF_V     = OFF_K + 16777216u;        // V^T [16][8][64][1024] bf16
static constexpr size_t OFF_O     = OFF_HT;                   // alias: hnorm_t dead after QKV gemm

static constexpr float QSC = 0.125f * 1.44269504f;  // softmax scale * log2(e), folded into Q

__device__ __forceinline__ unsigned short f2bf(float f) {
  unsigned int u = __float_as_uint(f);
  u += 0x7fffu + ((u >> 16) & 1u);
  return (unsigned short)(u >> 16);
}

// async global->LDS, 16B per lane; LDS dest = wave-uniform base + lane*16
__device__ __forceinline__ void gl_lds16(const unsigned short* g, unsigned short* lds_base) {
  __builtin_amdgcn_global_load_lds(
      (const __attribute__((address_space(1))) unsigned int*)g,
      (__attribute__((address_space(3))) unsigned int*)(unsigned int)(unsigned long long)lds_base,
      16, 0, 0);
}

// ---------------- weight fp32 -> bf16 ----------------
__global__ __launch_bounds__(256) void wconv_k(const float* __restrict__ w0, const float* __restrict__ w1,
                                               const float* __restrict__ w2, const float* __restrict__ w3,
                                               unsigned short* __restrict__ dst) {
  const float* srcs[4] = {w0, w1, w2, w3};
  const float* src = srcs[blockIdx.y];
  unsigned short* d = dst + (size_t)blockIdx.y * 262144u;
  int i = (blockIdx.x * 256 + threadIdx.x) * 4;
  float4 v = *(const float4*)(src + i);
  unsigned int lo = (unsigned int)f2bf(v.x) | ((unsigned int)f2bf(v.y) << 16);
  unsigned int hi = (unsigned int)f2bf(v.z) | ((unsigned int)f2bf(v.w) << 16);
  uint2 pk; pk.x = lo; pk.y = hi;
  *(uint2*)(d + i) = pk;
}

// ---------------- groupnorm stats: 128 blocks = (b,g) ----------------
__global__ __launch_bounds__(256) void gn_stats_k(const float* __restrict__ x, float* __restrict__ stats) {
  int bg = blockIdx.x;
  const float* p = x + (size_t)bg * 65536u;
  int t = threadIdx.x;
  float s = 0.f, ss = 0.f;
  for (int i = t * 4; i < 65536; i += 1024) {
    float4 v = *(const float4*)(p + i);
    s += v.x + v.y + v.z + v.w;
    ss += v.x * v.x + v.y * v.y + v.z * v.z + v.w * v.w;
  }
  for (int m = 1; m <= 32; m <<= 1) { s += __shfl_xor(s, m); ss += __shfl_xor(ss, m); }
  __shared__ float rs[4], rss[4];
  int wv = t >> 6;
  if ((t & 63) == 0) { rs[wv] = s; rss[wv] = ss; }
  __syncthreads();
  if (t == 0) {
    s = rs[0] + rs[1] + rs[2] + rs[3];
    ss = rss[0] + rss[1] + rss[2] + rss[3];
    float mean = s * (1.f / 65536.f);
    float var = ss * (1.f / 65536.f) - mean * mean;
    stats[bg * 2] = mean;
    stats[bg * 2 + 1] = rsqrtf(var + 1e-6f);
  }
}

// ---------------- groupnorm apply + transpose to [b][s][c] bf16 ----------------
__global__ __launch_bounds__(256) void gn_apply_k(const float* __restrict__ x, const float* __restrict__ scale,
                                                  const float* __restrict__ bias, const float* __restrict__ stats,
                                                  unsigned short* __restrict__ ht) {
  __shared__ float tile[64][65];
  int blk = blockIdx.x;
  int b = blk >> 9, cblk = (blk >> 6) & 7, sblk = blk & 63;
  int c0 = cblk * 64, s0 = sblk * 64;
  int t = threadIdx.x;
#pragma unroll
  for (int p = 0; p < 4; ++p) {
    int i = p * 16 + (t >> 4);
    int j = (t & 15) * 4;
    int c = c0 + i;
    float mean = stats[(b * 32 + (c >> 4)) * 2];
    float rstd = stats[(b * 32 + (c >> 4)) * 2 + 1];
    float a = rstd * scale[c];
    float b2 = bias[c] - mean * a;
    float4 v = *(const float4*)(x + ((size_t)(b * 512 + c)) * 4096u + s0 + j);
    tile[i][j + 0] = v.x * a + b2;
    tile[i][j + 1] = v.y * a + b2;
    tile[i][j + 2] = v.z * a + b2;
    tile[i][j + 3] = v.w * a + b2;
  }
  __syncthreads();
#pragma unroll
  for (int p = 0; p < 8; ++p) {
    int jj = p * 8 + (t >> 5);
    int c2 = (t & 31) * 2;
    unsigned int pk = (unsigned int)f2bf(tile[c2][jj]) | ((unsigned int)f2bf(tile[c2 + 1][jj]) << 16);
    *(unsigned int*)(ht + ((size_t)b * 4096u + s0 + jj) * 512u + c0 + c2) = pk;
  }
}

// ---------------- QKV projection GEMM (R4 single-buffer form) ----------------
// z = proj*4 + b.  proj 0,1 (Q,K): D[s][o] -> Q/K att layout.  proj 2 (V): D[o][s] -> V^T layout.
// Q output is pre-scaled by QSC (softmax scale folded in).
__global__ __launch_bounds__(256, 2) void qkv_gemm_k(const unsigned short* __restrict__ wbf,
                                                     const unsigned short* __restrict__ ht,
                                                     const float* __restrict__ bq, const float* __restrict__ bk,
                                                     const float* __restrict__ bv,
                                                     unsigned short* __restrict__ Qatt,
                                                     unsigned short* __restrict__ Katt,
                                                     unsigned short* __restrict__ Vt) {
  int proj = blockIdx.z >> 2, b = blockIdx.z & 3;
  const unsigned short* W = wbf + (size_t)proj * 262144u;
  const float* biasp = (proj == 0) ? bq : (proj == 1) ? bk : bv;
  int o0 = blockIdx.x * 128, s0 = blockIdx.y * 128;
  __shared__ unsigned short Wl[128 * 72];
  __shared__ unsigned short Xl[128 * 72];
  int t = threadIdx.x, lane = t & 63, wv = t >> 6;
  int col_l = lane & 31, half = lane >> 5;
  int qm = (wv >> 1) * 64, qn = (wv & 1) * 64;
  f32x16 acc[2][2];
#pragma unroll
  for (int i = 0; i < 2; i++)
#pragma unroll
    for (int j = 0; j < 2; j++)
#pragma unroll
      for (int r = 0; r < 16; r++) acc[i][j][r] = 0.f;

  const unsigned short* hb = ht + ((size_t)b * 4096u + s0) * 512u;
  for (int kb = 0; kb < 512; kb += 64) {
    __syncthreads();
    {
      int row = t >> 3, ch = (t & 7) * 8;
#pragma unroll
      for (int p = 0; p < 4; ++p, row += 32) {
        *(uint4*)(Wl + row * 72 + ch) = *(const uint4*)(W + (size_t)(o0 + row) * 512u + kb + ch);
        *(uint4*)(Xl + row * 72 + ch) = *(const uint4*)(hb + (size_t)row * 512u + kb + ch);
      }
    }
    __syncthreads();
    const unsigned short* aT = (proj == 2) ? Wl : Xl;
    const unsigned short* bT = (proj == 2) ? Xl : Wl;
#pragma unroll
    for (int ks = 0; ks < 64; ks += 16) {
      bf16x8 a0 = *(const bf16x8*)(aT + (qm + col_l) * 72 + ks + 8 * half);
      bf16x8 a1 = *(const bf16x8*)(aT + (qm + 32 + col_l) * 72 + ks + 8 * half);
      bf16x8 b0 = *(const bf16x8*)(bT + (qn + col_l) * 72 + ks + 8 * half);
      bf16x8 b1 = *(const bf16x8*)(bT + (qn + 32 + col_l) * 72 + ks + 8 * half);
      acc[0][0] = MFMA32(a0, b0, acc[0][0]);
      acc[0][1] = MFMA32(a0, b1, acc[0][1]);
      acc[1][0] = MFMA32(a1, b0, acc[1][0]);
      acc[1][1] = MFMA32(a1, b1, acc[1][1]);
    }
  }

  if (proj <= 1) {
    unsigned short* dst = (proj == 0) ? Qatt : Katt;
    float osc = (proj == 0) ? QSC : 1.0f;
#pragma unroll
    for (int i = 0; i < 2; i++)
#pragma unroll
      for (int j = 0; j < 2; j++) {
        int o = o0 + qn + 32 * j + col_l;
        int head = o >> 6, dd = o & 63;
        float bb = biasp[o];
#pragma unroll
        for (int r = 0; r < 16; r++) {
          int s = s0 + qm + 32 * i + ROWOF(r, half);
          int h = s >> 6, w = s & 63;
          int win = b * 4 + (h >> 5) * 2 + (w >> 5);
          int n = ((h & 31) << 5) | (w & 31);
          dst[(((size_t)(win * 8 + head)) * 1024u + n) * 64u + dd] = f2bf((acc[i][j][r] + bb) * osc);
        }
      }
  } else {
#pragma unroll
    for (int i = 0; i < 2; i++)
#pragma unroll
      for (int j = 0; j < 2; j++) {
        int s = s0 + qn + 32 * j + col_l;
        int h = s >> 6, w = s & 63;
        int win = b * 4 + (h >> 5) * 2 + (w >> 5);
        int n = ((h & 31) << 5) | (w & 31);
#pragma unroll
        for (int r = 0; r < 16; r++) {
          int o = o0 + qm + 32 * i + ROWOF(r, half);
          int head = o >> 6, dd = o & 63;
          Vt[(((size_t)(win * 8 + head)) * 64u + dd) * 1024u + n] = f2bf(acc[i][j][r] + biasp[o]);
        }
      }
  }
}

// ---------------- flash attention v7: 64-key tiles, async dbuf, 4 blocks/CU ----------------
// grid (x = win*8+head [128], y = rb [8]), 256 thr. XCD swizzle as R4.
// LDS = 2*(8K+8K) = 32 KB; launch_bounds(256,4) -> 4 waves/SIMD target.
// Tiles unpadded, 16B XOR swizzle (chunk j at row r stored at j^(r&7)).
__global__ __launch_bounds__(256, 4) void attn_k(const unsigned short* __restrict__ Qatt,
                                                 const unsigned short* __restrict__ Katt,
                                                 const unsigned short* __restrict__ Vt,
                                                 unsigned short* __restrict__ Oimg) {
  int wh_idx = blockIdx.x, rb = blockIdx.y;
  int win = wh_idx >> 3, head = wh_idx & 7;
  int t = threadIdx.x, lane = t & 63, wv = t >> 6;
  int col_l = lane & 31, half = lane >> 5;
  __shared__ unsigned short Kl[2][64 * 64];  // K tile [n=64][d=64], xor-swizzled
  __shared__ unsigned short Vl[2][64 * 64];  // V^T tile [d=64][n=64], xor-swizzled
  const size_t wh = (size_t)wh_idx;
  const unsigned short* Qb = Qatt + wh * 65536u;
  const unsigned short* Kb = Katt + wh * 65536u;
  const unsigned short* Vb = Vt + wh * 65536u;

  // staging: 512 slots (16B) per tile, 2 per thread: slot = wv*128 + i*64 + lane
  int sl0 = wv * 128 + lane, sl1 = sl0 + 64;
  int r0 = sl0 >> 3, off0 = ((sl0 & 7) ^ (r0 & 7)) * 8;
  int r1 = sl1 >> 3, off1 = ((sl1 & 7) ^ (r1 & 7)) * 8;
  unsigned short* Kd0 = &Kl[0][0] + wv * 1024;  // dst base (wave-uniform), call i adds i*512
  unsigned short* Vd0 = &Vl[0][0] + wv * 1024;

  // issue kt=0 tile loads
  gl_lds16(Kb + (size_t)r0 * 64u + off0, Kd0);
  gl_lds16(Kb + (size_t)r1 * 64u + off1, Kd0 + 512);
  gl_lds16(Vb + (size_t)r0 * 1024u + off0, Vd0);
  gl_lds16(Vb + (size_t)r1 * 1024u + off1, Vd0 + 512);

  int qrow = rb * 128 + wv * 32 + col_l;
  bf16x8 qf[4];
#pragma unroll
  for (int kk = 0; kk < 4; kk++) qf[kk] = *(const bf16x8*)(Qb + (size_t)qrow * 64u + kk * 16 + 8 * half);

  f32x16 oacc[2];
#pragma unroll
  for (int j = 0; j < 2; j++)
#pragma unroll
    for (int r = 0; r < 16; r++) oacc[j][r] = 0.f;
  float lsum = 0.f;

  const int kx = col_l & 7;  // row xor key (row = jb*32+col_l or dblk*32+col_l; 32%8==0)

  for (int kt = 0; kt < 16; ++kt) {
    const unsigned short* Kc = Kl[kt & 1];
    const unsigned short* Vc = Vl[kt & 1];
    __builtin_amdgcn_s_waitcnt(0x0F70);  // vmcnt(0): this wave's kt-tile DMA done
    __syncthreads();                     // all waves' DMA done; prev compute done
    if (kt < 15) {
      unsigned short* Kn = &Kl[(kt + 1) & 1][0] + wv * 1024;
      unsigned short* Vn = &Vl[(kt + 1) & 1][0] + wv * 1024;
      int nk = (kt + 1) * 64;
      gl_lds16(Kb + (size_t)(nk + r0) * 64u + off0, Kn);
      gl_lds16(Kb + (size_t)(nk + r1) * 64u + off1, Kn + 512);
      gl_lds16(Vb + (size_t)r0 * 1024u + nk + off0, Vn);
      gl_lds16(Vb + (size_t)r1 * 1024u + nk + off1, Vn + 512);
    }

    // S^T tile: [64 keys x 32 q], A = K rows, B = Q rows (as cols)
    f32x16 sacc[2];
#pragma unroll
    for (int jb = 0; jb < 2; jb++)
#pragma unroll
      for (int r = 0; r < 16; r++) sacc[jb][r] = 0.f;
#pragma unroll
    for (int jb = 0; jb < 2; jb++) {
      const unsigned short* Krow = Kc + (jb * 32 + col_l) * 64;
#pragma unroll
      for (int kk = 0; kk < 4; kk++) {
        bf16x8 af = *(const bf16x8*)(Krow + (((kk * 2 + half) ^ kx) * 8));
        sacc[jb] = MFMA32(af, qf[kk], sacc[jb]);
      }
    }

    // per 32-key block: exp2 (scale pre-folded into Q) -> pack bf16 -> half-wave exchange -> PV
#pragma unroll
    for (int jb = 0; jb < 2; jb++) {
      float p[16];
#pragma unroll
      for (int r = 0; r < 16; r++) p[r] = __builtin_amdgcn_exp2f(sacc[jb][r]);
      float ps = ((p[0] + p[1]) + (p[2] + p[3])) + ((p[4] + p[5]) + (p[6] + p[7]));
      ps += ((p[8] + p[9]) + (p[10] + p[11])) + ((p[12] + p[13]) + (p[14] + p[15]));
      lsum += ps;
      unsigned int pk[8];
#pragma unroll
      for (int j = 0; j < 8; j++)
        pk[j] = __builtin_amdgcn_perm(__float_as_uint(p[2 * j + 1]), __float_as_uint(p[2 * j]), 0x07060302u);
      // exchange with lane^32 to build A-operand fragments
      unsigned int rA = __shfl_xor((int)(half ? pk[0] : pk[2]), 32);
      unsigned int rB = __shfl_xor((int)(half ? pk[1] : pk[3]), 32);
      unsigned int rC = __shfl_xor((int)(half ? pk[4] : pk[6]), 32);
      unsigned int rD = __shfl_xor((int)(half ? pk[5] : pk[7]), 32);
      u32x4 f0, f1;
      f0[0] = half ? rA : pk[0];
      f0[1] = half ? rB : pk[1];
      f0[2] = half ? pk[2] : rA;
      f0[3] = half ? pk[3] : rB;
      f1[0] = half ? rC : pk[4];
      f1[1] = half ? rD : pk[5];
      f1[2] = half ? pk[6] : rC;
      f1[3] = half ? pk[7] : rD;
      bf16x8 pa0 = __builtin_bit_cast(bf16x8, f0);
      bf16x8 pa1 = __builtin_bit_cast(bf16x8, f1);
#pragma unroll
      for (int dblk = 0; dblk < 2; dblk++) {
        const unsigned short* Vrow = Vc + (dblk * 32 + col_l) * 64;
        bf16x8 v0 = *(const bf16x8*)(Vrow + (((jb * 4 + half) ^ kx) * 8));
        bf16x8 v1 = *(const bf16x8*)(Vrow + (((jb * 4 + 2 + half) ^ kx) * 8));
        oacc[dblk] = MFMA32(pa0, v0, oacc[dblk]);
        oacc[dblk] = MFMA32(pa1, v1, oacc[dblk]);
      }
    }
  }

  float l = lsum + __shfl_xor(lsum, 32);
  float inv = 1.f / l;

  int b = win >> 2, whn = (win >> 1) & 1, wwn = win & 1;
#pragma unroll
  for (int r = 0; r < 16; r++) {
    int qr = ROWOF(r, half);
    float invr = __shfl(inv, qr);
    int ntok = rb * 128 + wv * 32 + qr;
    int h = whn * 32 + (ntok >> 5), w = wwn * 32 + (ntok & 31);
    int s = h * 64 + w;
    size_t rowbase = ((size_t)b * 4096u + s) * 512u + head * 64;
    Oimg[rowbase + col_l] = f2bf(oacc[0][r] * invr);
    Oimg[rowbase + 32 + col_l] = f2bf(oacc[1][r] * invr);
  }
}

// ---------------- output projection + residual (R4 single-buffer form): D[o][s], grid (4,32,4) ----------------
__global__ __launch_bounds__(256, 2) void out_gemm_k(const unsigned short* __restrict__ wo_bf,
                                                     const unsigned short* __restrict__ Oimg,
                                                     const float* __restrict__ bo, const float* __restrict__ x,
                                                     float* __restrict__ out) {
  int b = blockIdx.z;
  int o0 = blockIdx.x * 128, s0 = blockIdx.y * 128;
  __shared__ unsigned short Wl[128 * 72];
  __shared__ unsigned short Xl[128 * 72];
  int t = threadIdx.x, lane = t & 63, wv = t >> 6;
  int col_l = lane & 31, half = lane >> 5;
  int qm = (wv >> 1) * 64, qn = (wv & 1) * 64;
  f32x16 acc[2][2];
#pragma unroll
  for (int i = 0; i < 2; i++)
#pragma unroll
    for (int j = 0; j < 2; j++)
#pragma unroll
      for (int r = 0; r < 16; r++) acc[i][j][r] = 0.f;

  const unsigned short* ob = Oimg + ((size_t)b * 4096u + s0) * 512u;
  for (int kb = 0; kb < 512; kb += 64) {
    __syncthreads();
    {
      int row = t >> 3, ch = (t & 7) * 8;
#pragma unroll
      for (int p = 0; p < 4; ++p, row += 32) {
        *(uint4*)(Wl + row * 72 + ch) = *(const uint4*)(wo_bf + (size_t)(o0 + row) * 512u + kb + ch);
        *(uint4*)(Xl + row * 72 + ch) = *(const uint4*)(ob + (size_t)row * 512u + kb + ch);
      }
    }
    __syncthreads();
#pragma unroll
    for (int ks = 0; ks < 64; ks += 16) {
      bf16x8 a0 = *(const bf16x8*)(Wl + (qm + col_l) * 72 + ks + 8 * half);
      bf16x8 a1 = *(const bf16x8*)(Wl + (qm + 32 + col_l) * 72 + ks + 8 * half);
      bf16x8 b0 = *(const bf16x8*)(Xl + (qn + col_l) * 72 + ks + 8 * half);
      bf16x8 b1 = *(const bf16x8*)(Xl + (qn + 32 + col_l) * 72 + ks + 8 * half);
      acc[0][0] = MFMA32(a0, b0, acc[0][0]);
      acc[0][1] = MFMA32(a0, b1, acc[0][1]);
      acc[1][0] = MFMA32(a1, b0, acc[1][0]);
      acc[1][1] = MFMA32(a1, b1, acc[1][1]);
    }
  }
#pragma unroll
  for (int i = 0; i < 2; i++)
#pragma unroll
    for (int j = 0; j < 2; j++) {
      int s = s0 + qn + 32 * j + col_l;
#pragma unroll
      for (int r = 0; r < 16; r++) {
        int o = o0 + qm + 32 * i + ROWOF(r, half);
        size_t idx = ((size_t)b * 512u + o) * 4096u + s;
        out[idx] = x[idx] + acc[i][j][r] + bo[o];
      }
    }
}

extern "C" void kernel_launch(void* const* d_in, const int* in_sizes, int n_in,
                              void* d_out, int out_size, void* d_ws, size_t ws_size,
                              hipStream_t stream) {
  const float* x = (const float*)d_in[0];
  const float* nsc = (const float*)d_in[1];
  const float* nbi = (const float*)d_in[2];
  const float* wq = (const float*)d_in[3];
  const float* bq = (const float*)d_in[4];
  const float* wk = (const float*)d_in[5];
  const float* bk = (const float*)d_in[6];
  const float* wvp = (const float*)d_in[7];
  const float* bv = (const float*)d_in[8];
  const float* wo = (const float*)d_in[9];
  const float* bo = (const float*)d_in[10];
  float* out = (float*)d_out;
  char* ws = (char*)d_ws;

  float* stats = (float*)(ws + OFF_STATS);
  unsigned short* wbf = (unsigned short*)(ws + OFF_W);
  unsigned short* ht = (unsigned short*)(ws + OFF_HT);
  unsigned short* Qatt = (unsigned short*)(ws + OFF_Q);
  unsigned short* Katt = (unsigned short*)(ws + OFF_K);
  unsigned short* Vt = (unsigned short*)(ws + OFF_V);
  unsigned short* Oimg = (unsigned short*)(ws + OFF_O);

  wconv_k<<<dim3(256, 4), 256, 0, stream>>>(wq, wk, wvp, wo, wbf);
  gn_stats_k<<<128, 256, 0, stream>>>(x, stats);
  gn_apply_k<<<2048, 256, 0, stream>>>(x, nsc, nbi, stats, ht);
  qkv_gemm_k<<<dim3(4, 32, 12), 256, 0, stream>>>(wbf, ht, bq, bk, bv, Qatt, Katt, Vt);
  attn_k<<<dim3(128, 8), 256, 0, stream>>>(Qatt, Katt, Vt, Oimg);
  out_gemm_k<<<dim3(4, 32, 4), 256, 0, stream>>>(wbf + 3u * 262144u, Oimg, bo, x, out);
}

// Round 8
// 249.681 us; speedup vs baseline: 1.3021x; 1.0555x over previous
//
#include <hip/hip_runtime.h>
#include <math.h>

typedef __bf16 bf16_t;
typedef bf16_t bf16x8 __attribute__((ext_vector_type(8)));
typedef float f32x16 __attribute__((ext_vector_type(16)));
typedef unsigned int u32x4 __attribute__((ext_vector_type(4)));

#define MFMA32(a, b, c) __builtin_amdgcn_mfma_f32_32x32x16_bf16(a, b, c, 0, 0, 0)
#define ROWOF(r, h) (((r) & 3) + 8 * ((r) >> 2) + 4 * (h))

// ---- problem constants ----
// B=4, C=512, H=W=64, WS=32, NH=8 heads, DH=64, GROUPS=32 (16 ch/group)
// windows: 16 total (b*4 + wh*2 + ww), tokens n=1024 per window

// ---- workspace layout (bytes) ----
static constexpr size_t OFF_STATS = 0;                        // 128*2 f32
static constexpr size_t OFF_W     = 4096;                     // 4 x 512*512 bf16 = 2 MB
static constexpr size_t OFF_HT    = OFF_W + 4u * 524288u;     // hnorm_t [4][4096][512] bf16 (aliased w/ Oimg_t)
static constexpr size_t OFF_Q     = OFF_HT + 16777216u;       // Q [16][8][1024][64] bf16 (pre-scaled by 0.125*log2e)
static constexpr size_t OFF_K     = OFF_Q + 16777216u;
static constexpr size_t OFF_V     = OFF_K + 16777216u;        // V^T [16][8][64][1024] bf16
static constexpr size_t OFF_O     = OFF_HT;                   // alias: hnorm_t dead after QKV gemm

static constexpr float QSC = 0.125f * 1.44269504f;  // softmax scale * log2(e), folded into Q

__device__ __forceinline__ unsigned short f2bf(float f) {
  unsigned int u = __float_as_uint(f);
  u += 0x7fffu + ((u >> 16) & 1u);
  return (unsigned short)(u >> 16);
}

// async global->LDS, 16B per lane; LDS dest = wave-uniform base + lane*16
__device__ __forceinline__ void gl_lds16(const unsigned short* g, unsigned short* lds_base) {
  __builtin_amdgcn_global_load_lds(
      (const __attribute__((address_space(1))) unsigned int*)g,
      (__attribute__((address_space(3))) unsigned int*)(unsigned int)(unsigned long long)lds_base,
      16, 0, 0);
}

// ---------------- weight fp32 -> bf16 ----------------
__global__ __launch_bounds__(256) void wconv_k(const float* __restrict__ w0, const float* __restrict__ w1,
                                               const float* __restrict__ w2, const float* __restrict__ w3,
                                               unsigned short* __restrict__ dst) {
  const float* srcs[4] = {w0, w1, w2, w3};
  const float* src = srcs[blockIdx.y];
  unsigned short* d = dst + (size_t)blockIdx.y * 262144u;
  int i = (blockIdx.x * 256 + threadIdx.x) * 4;
  float4 v = *(const float4*)(src + i);
  unsigned int lo = (unsigned int)f2bf(v.x) | ((unsigned int)f2bf(v.y) << 16);
  unsigned int hi = (unsigned int)f2bf(v.z) | ((unsigned int)f2bf(v.w) << 16);
  uint2 pk; pk.x = lo; pk.y = hi;
  *(uint2*)(d + i) = pk;
}

// ---------------- groupnorm stats: 128 blocks = (b,g) ----------------
__global__ __launch_bounds__(256) void gn_stats_k(const float* __restrict__ x, float* __restrict__ stats) {
  int bg = blockIdx.x;
  const float* p = x + (size_t)bg * 65536u;
  int t = threadIdx.x;
  float s = 0.f, ss = 0.f;
  for (int i = t * 4; i < 65536; i += 1024) {
    float4 v = *(const float4*)(p + i);
    s += v.x + v.y + v.z + v.w;
    ss += v.x * v.x + v.y * v.y + v.z * v.z + v.w * v.w;
  }
  for (int m = 1; m <= 32; m <<= 1) { s += __shfl_xor(s, m); ss += __shfl_xor(ss, m); }
  __shared__ float rs[4], rss[4];
  int wv = t >> 6;
  if ((t & 63) == 0) { rs[wv] = s; rss[wv] = ss; }
  __syncthreads();
  if (t == 0) {
    s = rs[0] + rs[1] + rs[2] + rs[3];
    ss = rss[0] + rss[1] + rss[2] + rss[3];
    float mean = s * (1.f / 65536.f);
    float var = ss * (1.f / 65536.f) - mean * mean;
    stats[bg * 2] = mean;
    stats[bg * 2 + 1] = rsqrtf(var + 1e-6f);
  }
}

// ---------------- groupnorm apply + transpose to [b][s][c] bf16 ----------------
__global__ __launch_bounds__(256) void gn_apply_k(const float* __restrict__ x, const float* __restrict__ scale,
                                                  const float* __restrict__ bias, const float* __restrict__ stats,
                                                  unsigned short* __restrict__ ht) {
  __shared__ float tile[64][65];
  int blk = blockIdx.x;
  int b = blk >> 9, cblk = (blk >> 6) & 7, sblk = blk & 63;
  int c0 = cblk * 64, s0 = sblk * 64;
  int t = threadIdx.x;
#pragma unroll
  for (int p = 0; p < 4; ++p) {
    int i = p * 16 + (t >> 4);
    int j = (t & 15) * 4;
    int c = c0 + i;
    float mean = stats[(b * 32 + (c >> 4)) * 2];
    float rstd = stats[(b * 32 + (c >> 4)) * 2 + 1];
    float a = rstd * scale[c];
    float b2 = bias[c] - mean * a;
    float4 v = *(const float4*)(x + ((size_t)(b * 512 + c)) * 4096u + s0 + j);
    tile[i][j + 0] = v.x * a + b2;
    tile[i][j + 1] = v.y * a + b2;
    tile[i][j + 2] = v.z * a + b2;
    tile[i][j + 3] = v.w * a + b2;
  }
  __syncthreads();
#pragma unroll
  for (int p = 0; p < 8; ++p) {
    int jj = p * 8 + (t >> 5);
    int c2 = (t & 31) * 2;
    unsigned int pk = (unsigned int)f2bf(tile[c2][jj]) | ((unsigned int)f2bf(tile[c2 + 1][jj]) << 16);
    *(unsigned int*)(ht + ((size_t)b * 4096u + s0 + jj) * 512u + c0 + c2) = pk;
  }
}

// ---------------- QKV projection GEMM (R4 single-buffer form) ----------------
// z = proj*4 + b.  proj 0,1 (Q,K): D[s][o] -> Q/K att layout.  proj 2 (V): D[o][s] -> V^T layout.
// Q output is pre-scaled by QSC (softmax scale folded in).
__global__ __launch_bounds__(256, 2) void qkv_gemm_k(const unsigned short* __restrict__ wbf,
                                                     const unsigned short* __restrict__ ht,
                                                     const float* __restrict__ bq, const float* __restrict__ bk,
                                                     const float* __restrict__ bv,
                                                     unsigned short* __restrict__ Qatt,
                                                     unsigned short* __restrict__ Katt,
                                                     unsigned short* __restrict__ Vt) {
  int proj = blockIdx.z >> 2, b = blockIdx.z & 3;
  const unsigned short* W = wbf + (size_t)proj * 262144u;
  const float* biasp = (proj == 0) ? bq : (proj == 1) ? bk : bv;
  int o0 = blockIdx.x * 128, s0 = blockIdx.y * 128;
  __shared__ unsigned short Wl[128 * 72];
  __shared__ unsigned short Xl[128 * 72];
  int t = threadIdx.x, lane = t & 63, wv = t >> 6;
  int col_l = lane & 31, half = lane >> 5;
  int qm = (wv >> 1) * 64, qn = (wv & 1) * 64;
  f32x16 acc[2][2];
#pragma unroll
  for (int i = 0; i < 2; i++)
#pragma unroll
    for (int j = 0; j < 2; j++)
#pragma unroll
      for (int r = 0; r < 16; r++) acc[i][j][r] = 0.f;

  const unsigned short* hb = ht + ((size_t)b * 4096u + s0) * 512u;
  for (int kb = 0; kb < 512; kb += 64) {
    __syncthreads();
    {
      int row = t >> 3, ch = (t & 7) * 8;
#pragma unroll
      for (int p = 0; p < 4; ++p, row += 32) {
        *(uint4*)(Wl + row * 72 + ch) = *(const uint4*)(W + (size_t)(o0 + row) * 512u + kb + ch);
        *(uint4*)(Xl + row * 72 + ch) = *(const uint4*)(hb + (size_t)row * 512u + kb + ch);
      }
    }
    __syncthreads();
    const unsigned short* aT = (proj == 2) ? Wl : Xl;
    const unsigned short* bT = (proj == 2) ? Xl : Wl;
#pragma unroll
    for (int ks = 0; ks < 64; ks += 16) {
      bf16x8 a0 = *(const bf16x8*)(aT + (qm + col_l) * 72 + ks + 8 * half);
      bf16x8 a1 = *(const bf16x8*)(aT + (qm + 32 + col_l) * 72 + ks + 8 * half);
      bf16x8 b0 = *(const bf16x8*)(bT + (qn + col_l) * 72 + ks + 8 * half);
      bf16x8 b1 = *(const bf16x8*)(bT + (qn + 32 + col_l) * 72 + ks + 8 * half);
      acc[0][0] = MFMA32(a0, b0, acc[0][0]);
      acc[0][1] = MFMA32(a0, b1, acc[0][1]);
      acc[1][0] = MFMA32(a1, b0, acc[1][0]);
      acc[1][1] = MFMA32(a1, b1, acc[1][1]);
    }
  }

  if (proj <= 1) {
    unsigned short* dst = (proj == 0) ? Qatt : Katt;
    float osc = (proj == 0) ? QSC : 1.0f;
#pragma unroll
    for (int i = 0; i < 2; i++)
#pragma unroll
      for (int j = 0; j < 2; j++) {
        int o = o0 + qn + 32 * j + col_l;
        int head = o >> 6, dd = o & 63;
        float bb = biasp[o];
#pragma unroll
        for (int r = 0; r < 16; r++) {
          int s = s0 + qm + 32 * i + ROWOF(r, half);
          int h = s >> 6, w = s & 63;
          int win = b * 4 + (h >> 5) * 2 + (w >> 5);
          int n = ((h & 31) << 5) | (w & 31);
          dst[(((size_t)(win * 8 + head)) * 1024u + n) * 64u + dd] = f2bf((acc[i][j][r] + bb) * osc);
        }
      }
  } else {
#pragma unroll
    for (int i = 0; i < 2; i++)
#pragma unroll
      for (int j = 0; j < 2; j++) {
        int s = s0 + qn + 32 * j + col_l;
        int h = s >> 6, w = s & 63;
        int win = b * 4 + (h >> 5) * 2 + (w >> 5);
        int n = ((h & 31) << 5) | (w & 31);
#pragma unroll
        for (int r = 0; r < 16; r++) {
          int o = o0 + qm + 32 * i + ROWOF(r, half);
          int head = o >> 6, dd = o & 63;
          Vt[(((size_t)(win * 8 + head)) * 64u + dd) * 1024u + n] = f2bf(acc[i][j][r] + biasp[o]);
        }
      }
  }
}

// ---------------- flash attention v7: 64-key tiles, async dbuf, 4 blocks/CU ----------------
// grid (x = win*8+head [128], y = rb [8]), 256 thr. XCD swizzle as R4.
// LDS = 2*(8K+8K) = 32 KB; launch_bounds(256,4) -> 4 waves/SIMD target.
// Tiles unpadded, 16B XOR swizzle (chunk j at row r stored at j^(r&7)).
__global__ __launch_bounds__(256, 4) void attn_k(const unsigned short* __restrict__ Qatt,
                                                 const unsigned short* __restrict__ Katt,
                                                 const unsigned short* __restrict__ Vt,
                                                 unsigned short* __restrict__ Oimg) {
  int wh_idx = blockIdx.x, rb = blockIdx.y;
  int win = wh_idx >> 3, head = wh_idx & 7;
  int t = threadIdx.x, lane = t & 63, wv = t >> 6;
  int col_l = lane & 31, half = lane >> 5;
  __shared__ unsigned short Kl[2][64 * 64];  // K tile [n=64][d=64], xor-swizzled
  __shared__ unsigned short Vl[2][64 * 64];  // V^T tile [d=64][n=64], xor-swizzled
  const size_t wh = (size_t)wh_idx;
  const unsigned short* Qb = Qatt + wh * 65536u;
  const unsigned short* Kb = Katt + wh * 65536u;
  const unsigned short* Vb = Vt + wh * 65536u;

  // staging: 512 slots (16B) per tile, 2 per thread: slot = wv*128 + i*64 + lane
  int sl0 = wv * 128 + lane, sl1 = sl0 + 64;
  int r0 = sl0 >> 3, off0 = ((sl0 & 7) ^ (r0 & 7)) * 8;
  int r1 = sl1 >> 3, off1 = ((sl1 & 7) ^ (r1 & 7)) * 8;
  unsigned short* Kd0 = &Kl[0][0] + wv * 1024;  // dst base (wave-uniform), call i adds i*512
  unsigned short* Vd0 = &Vl[0][0] + wv * 1024;

  // issue kt=0 tile loads
  gl_lds16(Kb + (size_t)r0 * 64u + off0, Kd0);
  gl_lds16(Kb + (size_t)r1 * 64u + off1, Kd0 + 512);
  gl_lds16(Vb + (size_t)r0 * 1024u + off0, Vd0);
  gl_lds16(Vb + (size_t)r1 * 1024u + off1, Vd0 + 512);

  int qrow = rb * 128 + wv * 32 + col_l;
  bf16x8 qf[4];
#pragma unroll
  for (int kk = 0; kk < 4; kk++) qf[kk] = *(const bf16x8*)(Qb + (size_t)qrow * 64u + kk * 16 + 8 * half);

  f32x16 oacc[2];
#pragma unroll
  for (int j = 0; j < 2; j++)
#pragma unroll
    for (int r = 0; r < 16; r++) oacc[j][r] = 0.f;
  float lsum = 0.f;

  const int kx = col_l & 7;  // row xor key (row = jb*32+col_l or dblk*32+col_l; 32%8==0)

  for (int kt = 0; kt < 16; ++kt) {
    const unsigned short* Kc = Kl[kt & 1];
    const unsigned short* Vc = Vl[kt & 1];
    __builtin_amdgcn_s_waitcnt(0x0F70);  // vmcnt(0): this wave's kt-tile DMA done
    __syncthreads();                     // all waves' DMA done; prev compute done
    if (kt < 15) {
      unsigned short* Kn = &Kl[(kt + 1) & 1][0] + wv * 1024;
      unsigned short* Vn = &Vl[(kt + 1) & 1][0] + wv * 1024;
      int nk = (kt + 1) * 64;
      gl_lds16(Kb + (size_t)(nk + r0) * 64u + off0, Kn);
      gl_lds16(Kb + (size_t)(nk + r1) * 64u + off1, Kn + 512);
      gl_lds16(Vb + (size_t)r0 * 1024u + nk + off0, Vn);
      gl_lds16(Vb + (size_t)r1 * 1024u + nk + off1, Vn + 512);
    }

    // S^T tile: [64 keys x 32 q], A = K rows, B = Q rows (as cols)
    f32x16 sacc[2];
#pragma unroll
    for (int jb = 0; jb < 2; jb++)
#pragma unroll
      for (int r = 0; r < 16; r++) sacc[jb][r] = 0.f;
#pragma unroll
    for (int jb = 0; jb < 2; jb++) {
      const unsigned short* Krow = Kc + (jb * 32 + col_l) * 64;
#pragma unroll
      for (int kk = 0; kk < 4; kk++) {
        bf16x8 af = *(const bf16x8*)(Krow + (((kk * 2 + half) ^ kx) * 8));
        sacc[jb] = MFMA32(af, qf[kk], sacc[jb]);
      }
    }

    // per 32-key block: exp2 (scale pre-folded into Q) -> pack bf16 -> half-wave exchange -> PV
#pragma unroll
    for (int jb = 0; jb < 2; jb++) {
      float p[16];
#pragma unroll
      for (int r = 0; r < 16; r++) p[r] = __builtin_amdgcn_exp2f(sacc[jb][r]);
      float ps = ((p[0] + p[1]) + (p[2] + p[3])) + ((p[4] + p[5]) + (p[6] + p[7]));
      ps += ((p[8] + p[9]) + (p[10] + p[11])) + ((p[12] + p[13]) + (p[14] + p[15]));
      lsum += ps;
      unsigned int pk[8];
#pragma unroll
      for (int j = 0; j < 8; j++)
        pk[j] = __builtin_amdgcn_perm(__float_as_uint(p[2 * j + 1]), __float_as_uint(p[2 * j]), 0x07060302u);
      // exchange with lane^32 to build A-operand fragments
      unsigned int rA = __shfl_xor((int)(half ? pk[0] : pk[2]), 32);
      unsigned int rB = __shfl_xor((int)(half ? pk[1] : pk[3]), 32);
      unsigned int rC = __shfl_xor((int)(half ? pk[4] : pk[6]), 32);
      unsigned int rD = __shfl_xor((int)(half ? pk[5] : pk[7]), 32);
      u32x4 f0, f1;
      f0[0] = half ? rA : pk[0];
      f0[1] = half ? rB : pk[1];
      f0[2] = half ? pk[2] : rA;
      f0[3] = half ? pk[3] : rB;
      f1[0] = half ? rC : pk[4];
      f1[1] = half ? rD : pk[5];
      f1[2] = half ? pk[6] : rC;
      f1[3] = half ? pk[7] : rD;
      bf16x8 pa0 = __builtin_bit_cast(bf16x8, f0);
      bf16x8 pa1 = __builtin_bit_cast(bf16x8, f1);
#pragma unroll
      for (int dblk = 0; dblk < 2; dblk++) {
        const unsigned short* Vrow = Vc + (dblk * 32 + col_l) * 64;
        bf16x8 v0 = *(const bf16x8*)(Vrow + (((jb * 4 + half) ^ kx) * 8));
        bf16x8 v1 = *(const bf16x8*)(Vrow + (((jb * 4 + 2 + half) ^ kx) * 8));
        oacc[dblk] = MFMA32(pa0, v0, oacc[dblk]);
        oacc[dblk] = MFMA32(pa1, v1, oacc[dblk]);
      }
    }
  }

  float l = lsum + __shfl_xor(lsum, 32);
  float inv = 1.f / l;

  int b = win >> 2, whn = (win >> 1) & 1, wwn = win & 1;
#pragma unroll
  for (int r = 0; r < 16; r++) {
    int qr = ROWOF(r, half);
    float invr = __shfl(inv, qr);
    int ntok = rb * 128 + wv * 32 + qr;
    int h = whn * 32 + (ntok >> 5), w = wwn * 32 + (ntok & 31);
    int s = h * 64 + w;
    size_t rowbase = ((size_t)b * 4096u + s) * 512u + head * 64;
    Oimg[rowbase + col_l] = f2bf(oacc[0][r] * invr);
    Oimg[rowbase + 32 + col_l] = f2bf(oacc[1][r] * invr);
  }
}

// ---------------- output projection + residual: D[o][s], grid (4,32,4) ----------------
// v2: residual x tile prefetched into registers BEFORE the K-loop (64 batched
// loads, covered by MFMA loop) -> epilogue is add+store only, no vmcnt stalls.
__global__ __launch_bounds__(256, 2) void out_gemm_k(const unsigned short* __restrict__ wo_bf,
                                                     const unsigned short* __restrict__ Oimg,
                                                     const float* __restrict__ bo, const float* __restrict__ x,
                                                     float* __restrict__ out) {
  int b = blockIdx.z;
  int o0 = blockIdx.x * 128, s0 = blockIdx.y * 128;
  __shared__ unsigned short Wl[128 * 72];
  __shared__ unsigned short Xl[128 * 72];
  int t = threadIdx.x, lane = t & 63, wv = t >> 6;
  int col_l = lane & 31, half = lane >> 5;
  int qm = (wv >> 1) * 64, qn = (wv & 1) * 64;

  // batched residual prefetch (issued up front; completes during K-loop)
  float xv[2][2][16];
#pragma unroll
  for (int i = 0; i < 2; i++)
#pragma unroll
    for (int j = 0; j < 2; j++) {
      int s = s0 + qn + 32 * j + col_l;
#pragma unroll
      for (int r = 0; r < 16; r++) {
        int o = o0 + qm + 32 * i + ROWOF(r, half);
        xv[i][j][r] = x[((size_t)b * 512u + o) * 4096u + s];
      }
    }

  f32x16 acc[2][2];
#pragma unroll
  for (int i = 0; i < 2; i++)
#pragma unroll
    for (int j = 0; j < 2; j++)
#pragma unroll
      for (int r = 0; r < 16; r++) acc[i][j][r] = 0.f;

  const unsigned short* ob = Oimg + ((size_t)b * 4096u + s0) * 512u;
  for (int kb = 0; kb < 512; kb += 64) {
    __syncthreads();
    {
      int row = t >> 3, ch = (t & 7) * 8;
#pragma unroll
      for (int p = 0; p < 4; ++p, row += 32) {
        *(uint4*)(Wl + row * 72 + ch) = *(const uint4*)(wo_bf + (size_t)(o0 + row) * 512u + kb + ch);
        *(uint4*)(Xl + row * 72 + ch) = *(const uint4*)(ob + (size_t)row * 512u + kb + ch);
      }
    }
    __syncthreads();
#pragma unroll
    for (int ks = 0; ks < 64; ks += 16) {
      bf16x8 a0 = *(const bf16x8*)(Wl + (qm + col_l) * 72 + ks + 8 * half);
      bf16x8 a1 = *(const bf16x8*)(Wl + (qm + 32 + col_l) * 72 + ks + 8 * half);
      bf16x8 b0 = *(const bf16x8*)(Xl + (qn + col_l) * 72 + ks + 8 * half);
      bf16x8 b1 = *(const bf16x8*)(Xl + (qn + 32 + col_l) * 72 + ks + 8 * half);
      acc[0][0] = MFMA32(a0, b0, acc[0][0]);
      acc[0][1] = MFMA32(a0, b1, acc[0][1]);
      acc[1][0] = MFMA32(a1, b0, acc[1][0]);
      acc[1][1] = MFMA32(a1, b1, acc[1][1]);
    }
  }
#pragma unroll
  for (int i = 0; i < 2; i++)
#pragma unroll
    for (int j = 0; j < 2; j++) {
      int s = s0 + qn + 32 * j + col_l;
#pragma unroll
      for (int r = 0; r < 16; r++) {
        int o = o0 + qm + 32 * i + ROWOF(r, half);
        size_t idx = ((size_t)b * 512u + o) * 4096u + s;
        out[idx] = xv[i][j][r] + acc[i][j][r] + bo[o];
      }
    }
}

extern "C" void kernel_launch(void* const* d_in, const int* in_sizes, int n_in,
                              void* d_out, int out_size, void* d_ws, size_t ws_size,
                              hipStream_t stream) {
  const float* x = (const float*)d_in[0];
  const float* nsc = (const float*)d_in[1];
  const float* nbi = (const float*)d_in[2];
  const float* wq = (const float*)d_in[3];
  const float* bq = (const float*)d_in[4];
  const float* wk = (const float*)d_in[5];
  const float* bk = (const float*)d_in[6];
  const float* wvp = (const float*)d_in[7];
  const float* bv = (const float*)d_in[8];
  const float* wo = (const float*)d_in[9];
  const float* bo = (const float*)d_in[10];
  float* out = (float*)d_out;
  char* ws = (char*)d_ws;

  float* stats = (float*)(ws + OFF_STATS);
  unsigned short* wbf = (unsigned short*)(ws + OFF_W);
  unsigned short* ht = (unsigned short*)(ws + OFF_HT);
  unsigned short* Qatt = (unsigned short*)(ws + OFF_Q);
  unsigned short* Katt = (unsigned short*)(ws + OFF_K);
  unsigned short* Vt = (unsigned short*)(ws + OFF_V);
  unsigned short* Oimg = (unsigned short*)(ws + OFF_O);

  wconv_k<<<dim3(256, 4), 256, 0, stream>>>(wq, wk, wvp, wo, wbf);
  gn_stats_k<<<128, 256, 0, stream>>>(x, stats);
  gn_apply_k<<<2048, 256, 0, stream>>>(x, nsc, nbi, stats, ht);
  qkv_gemm_k<<<dim3(4, 32, 12), 256, 0, stream>>>(wbf, ht, bq, bk, bv, Qatt, Katt, Vt);
  attn_k<<<dim3(128, 8), 256, 0, stream>>>(Qatt, Katt, Vt, Oimg);
  out_gemm_k<<<dim3(4, 32, 4), 256, 0, stream>>>(wbf + 3u * 262144u, Oimg, bo, x, out);
}

// Round 9
// 229.074 us; speedup vs baseline: 1.4192x; 1.0900x over previous
//
#include <hip/hip_runtime.h>
#include <math.h>

typedef __bf16 bf16_t;
typedef bf16_t bf16x8 __attribute__((ext_vector_type(8)));
typedef float f32x16 __attribute__((ext_vector_type(16)));
typedef unsigned int u32x4 __attribute__((ext_vector_type(4)));

#define MFMA32(a, b, c) __builtin_amdgcn_mfma_f32_32x32x16_bf16(a, b, c, 0, 0, 0)
#define ROWOF(r, h) (((r) & 3) + 8 * ((r) >> 2) + 4 * (h))

// ---- problem constants ----
// B=4, C=512, H=W=64, WS=32, NH=8 heads, DH=64, GROUPS=32 (16 ch/group)
// windows: 16 total (b*4 + wh*2 + ww), tokens n=1024 per window

// ---- workspace layout (bytes) ----
static constexpr size_t OFF_STATS = 0;                        // stats_part [128][8][2] f32 = 8 KB
static constexpr size_t OFF_W     = 16384;                    // 4 x 512*512 bf16 = 2 MB
static constexpr size_t OFF_HT    = OFF_W + 4u * 524288u;     // hnorm_t [4][4096][512] bf16 (aliased w/ Oimg)
static constexpr size_t OFF_Q     = OFF_HT + 16777216u;       // Q [16][8][1024][64] bf16 (pre-scaled by 0.125*log2e)
static constexpr size_t OFF_K     = OFF_Q + 16777216u;
static constexpr size_t OFF_V     = OFF_K + 16777216u;        // V^T [16][8][64][1024] bf16
static constexpr size_t OFF_O     = OFF_HT;                   // alias: hnorm_t dead after QKV gemm

static constexpr float QSC = 0.125f * 1.44269504f;  // softmax scale * log2(e), folded into Q

__device__ __forceinline__ unsigned short f2bf(float f) {
  unsigned int u = __float_as_uint(f);
  u += 0x7fffu + ((u >> 16) & 1u);
  return (unsigned short)(u >> 16);
}

// async global->LDS, 16B per lane; LDS dest = wave-uniform base + lane*16
__device__ __forceinline__ void gl_lds16(const unsigned short* g, unsigned short* lds_base) {
  __builtin_amdgcn_global_load_lds(
      (const __attribute__((address_space(1))) unsigned int*)g,
      (__attribute__((address_space(3))) unsigned int*)(unsigned int)(unsigned long long)lds_base,
      16, 0, 0);
}

// ---------------- weight fp32 -> bf16 ----------------
__global__ __launch_bounds__(256) void wconv_k(const float* __restrict__ w0, const float* __restrict__ w1,
                                               const float* __restrict__ w2, const float* __restrict__ w3,
                                               unsigned short* __restrict__ dst) {
  const float* srcs[4] = {w0, w1, w2, w3};
  const float* src = srcs[blockIdx.y];
  unsigned short* d = dst + (size_t)blockIdx.y * 262144u;
  int i = (blockIdx.x * 256 + threadIdx.x) * 4;
  float4 v = *(const float4*)(src + i);
  unsigned int lo = (unsigned int)f2bf(v.x) | ((unsigned int)f2bf(v.y) << 16);
  unsigned int hi = (unsigned int)f2bf(v.z) | ((unsigned int)f2bf(v.w) << 16);
  uint2 pk; pk.x = lo; pk.y = hi;
  *(uint2*)(d + i) = pk;
}

// ---------------- groupnorm stats, split-8: grid (128 bg, 8 split) ----------------
// Each block partial-sums 8192 elems and writes stats_part[(bg*8+split)*2 + {0,1}].
// Deterministic: no atomics, no zero-init needed (all slots written).
__global__ __launch_bounds__(256) void gn_stats_k(const float* __restrict__ x, float* __restrict__ stats_part) {
  int bg = blockIdx.x, sp = blockIdx.y;
  const float* p = x + (size_t)bg * 65536u + (size_t)sp * 8192u;
  int t = threadIdx.x;
  float s = 0.f, ss = 0.f;
  for (int i = t * 4; i < 8192; i += 1024) {
    float4 v = *(const float4*)(p + i);
    s += v.x + v.y + v.z + v.w;
    ss += v.x * v.x + v.y * v.y + v.z * v.z + v.w * v.w;
  }
  for (int m = 1; m <= 32; m <<= 1) { s += __shfl_xor(s, m); ss += __shfl_xor(ss, m); }
  __shared__ float rs[4], rss[4];
  int wv = t >> 6;
  if ((t & 63) == 0) { rs[wv] = s; rss[wv] = ss; }
  __syncthreads();
  if (t == 0) {
    s = rs[0] + rs[1] + rs[2] + rs[3];
    ss = rss[0] + rss[1] + rss[2] + rss[3];
    stats_part[(bg * 8 + sp) * 2] = s;
    stats_part[(bg * 8 + sp) * 2 + 1] = ss;
  }
}

// ---------------- groupnorm apply + transpose to [b][s][c] bf16 ----------------
// Folds the 8 split-partials per group into mean/rstd in-block (4 groups/block).
__global__ __launch_bounds__(256) void gn_apply_k(const float* __restrict__ x, const float* __restrict__ scale,
                                                  const float* __restrict__ bias, const float* __restrict__ stats_part,
                                                  unsigned short* __restrict__ ht) {
  __shared__ float tile[64][65];
  __shared__ float gmean[4], grstd[4];
  int blk = blockIdx.x;
  int b = blk >> 9, cblk = (blk >> 6) & 7, sblk = blk & 63;
  int c0 = cblk * 64, s0 = sblk * 64;
  int t = threadIdx.x;
  if (t < 4) {
    int gg = b * 32 + (c0 >> 4) + t;
    float s = 0.f, ss = 0.f;
#pragma unroll
    for (int sp = 0; sp < 8; ++sp) {
      s += stats_part[(gg * 8 + sp) * 2];
      ss += stats_part[(gg * 8 + sp) * 2 + 1];
    }
    float mean = s * (1.f / 65536.f);
    float var = ss * (1.f / 65536.f) - mean * mean;
    gmean[t] = mean;
    grstd[t] = rsqrtf(var + 1e-6f);
  }
  __syncthreads();
#pragma unroll
  for (int p = 0; p < 4; ++p) {
    int i = p * 16 + (t >> 4);
    int j = (t & 15) * 4;
    int c = c0 + i;
    float a = grstd[i >> 4] * scale[c];
    float b2 = bias[c] - gmean[i >> 4] * a;
    float4 v = *(const float4*)(x + ((size_t)(b * 512 + c)) * 4096u + s0 + j);
    tile[i][j + 0] = v.x * a + b2;
    tile[i][j + 1] = v.y * a + b2;
    tile[i][j + 2] = v.z * a + b2;
    tile[i][j + 3] = v.w * a + b2;
  }
  __syncthreads();
#pragma unroll
  for (int p = 0; p < 8; ++p) {
    int jj = p * 8 + (t >> 5);
    int c2 = (t & 31) * 2;
    unsigned int pk = (unsigned int)f2bf(tile[c2][jj]) | ((unsigned int)f2bf(tile[c2 + 1][jj]) << 16);
    *(unsigned int*)(ht + ((size_t)b * 4096u + s0 + jj) * 512u + c0 + c2) = pk;
  }
}

// ---------------- QKV projection GEMM (single-buffer, 4 blocks/CU) ----------------
// z = proj*4 + b.  proj 0,1 (Q,K): D[s][o] -> Q/K att layout.  proj 2 (V): D[o][s] -> V^T layout.
// Q output is pre-scaled by QSC (softmax scale folded in).
__global__ __launch_bounds__(256, 4) void qkv_gemm_k(const unsigned short* __restrict__ wbf,
                                                     const unsigned short* __restrict__ ht,
                                                     const float* __restrict__ bq, const float* __restrict__ bk,
                                                     const float* __restrict__ bv,
                                                     unsigned short* __restrict__ Qatt,
                                                     unsigned short* __restrict__ Katt,
                                                     unsigned short* __restrict__ Vt) {
  int proj = blockIdx.z >> 2, b = blockIdx.z & 3;
  const unsigned short* W = wbf + (size_t)proj * 262144u;
  const float* biasp = (proj == 0) ? bq : (proj == 1) ? bk : bv;
  int o0 = blockIdx.x * 128, s0 = blockIdx.y * 128;
  __shared__ unsigned short Wl[128 * 72];
  __shared__ unsigned short Xl[128 * 72];
  int t = threadIdx.x, lane = t & 63, wv = t >> 6;
  int col_l = lane & 31, half = lane >> 5;
  int qm = (wv >> 1) * 64, qn = (wv & 1) * 64;
  f32x16 acc[2][2];
#pragma unroll
  for (int i = 0; i < 2; i++)
#pragma unroll
    for (int j = 0; j < 2; j++)
#pragma unroll
      for (int r = 0; r < 16; r++) acc[i][j][r] = 0.f;

  const unsigned short* hb = ht + ((size_t)b * 4096u + s0) * 512u;
  for (int kb = 0; kb < 512; kb += 64) {
    __syncthreads();
    {
      int row = t >> 3, ch = (t & 7) * 8;
#pragma unroll
      for (int p = 0; p < 4; ++p, row += 32) {
        *(uint4*)(Wl + row * 72 + ch) = *(const uint4*)(W + (size_t)(o0 + row) * 512u + kb + ch);
        *(uint4*)(Xl + row * 72 + ch) = *(const uint4*)(hb + (size_t)row * 512u + kb + ch);
      }
    }
    __syncthreads();
    const unsigned short* aT = (proj == 2) ? Wl : Xl;
    const unsigned short* bT = (proj == 2) ? Xl : Wl;
#pragma unroll
    for (int ks = 0; ks < 64; ks += 16) {
      bf16x8 a0 = *(const bf16x8*)(aT + (qm + col_l) * 72 + ks + 8 * half);
      bf16x8 a1 = *(const bf16x8*)(aT + (qm + 32 + col_l) * 72 + ks + 8 * half);
      bf16x8 b0 = *(const bf16x8*)(bT + (qn + col_l) * 72 + ks + 8 * half);
      bf16x8 b1 = *(const bf16x8*)(bT + (qn + 32 + col_l) * 72 + ks + 8 * half);
      acc[0][0] = MFMA32(a0, b0, acc[0][0]);
      acc[0][1] = MFMA32(a0, b1, acc[0][1]);
      acc[1][0] = MFMA32(a1, b0, acc[1][0]);
      acc[1][1] = MFMA32(a1, b1, acc[1][1]);
    }
  }

  if (proj <= 1) {
    unsigned short* dst = (proj == 0) ? Qatt : Katt;
    float osc = (proj == 0) ? QSC : 1.0f;
#pragma unroll
    for (int i = 0; i < 2; i++)
#pragma unroll
      for (int j = 0; j < 2; j++) {
        int o = o0 + qn + 32 * j + col_l;
        int head = o >> 6, dd = o & 63;
        float bb = biasp[o];
#pragma unroll
        for (int r = 0; r < 16; r++) {
          int s = s0 + qm + 32 * i + ROWOF(r, half);
          int h = s >> 6, w = s & 63;
          int win = b * 4 + (h >> 5) * 2 + (w >> 5);
          int n = ((h & 31) << 5) | (w & 31);
          dst[(((size_t)(win * 8 + head)) * 1024u + n) * 64u + dd] = f2bf((acc[i][j][r] + bb) * osc);
        }
      }
  } else {
#pragma unroll
    for (int i = 0; i < 2; i++)
#pragma unroll
      for (int j = 0; j < 2; j++) {
        int s = s0 + qn + 32 * j + col_l;
        int h = s >> 6, w = s & 63;
        int win = b * 4 + (h >> 5) * 2 + (w >> 5);
        int n = ((h & 31) << 5) | (w & 31);
#pragma unroll
        for (int r = 0; r < 16; r++) {
          int o = o0 + qm + 32 * i + ROWOF(r, half);
          int head = o >> 6, dd = o & 63;
          Vt[(((size_t)(win * 8 + head)) * 64u + dd) * 1024u + n] = f2bf(acc[i][j][r] + biasp[o]);
        }
      }
  }
}

// ---------------- flash attention v7: 64-key tiles, async dbuf, 4 blocks/CU ----------------
// grid (x = win*8+head [128], y = rb [8]), 256 thr. XCD swizzle as R4.
// LDS = 2*(8K+8K) = 32 KB; launch_bounds(256,4) -> 4 waves/SIMD target.
// Tiles unpadded, 16B XOR swizzle (chunk j at row r stored at j^(r&7)).
__global__ __launch_bounds__(256, 4) void attn_k(const unsigned short* __restrict__ Qatt,
                                                 const unsigned short* __restrict__ Katt,
                                                 const unsigned short* __restrict__ Vt,
                                                 unsigned short* __restrict__ Oimg) {
  int wh_idx = blockIdx.x, rb = blockIdx.y;
  int win = wh_idx >> 3, head = wh_idx & 7;
  int t = threadIdx.x, lane = t & 63, wv = t >> 6;
  int col_l = lane & 31, half = lane >> 5;
  __shared__ unsigned short Kl[2][64 * 64];  // K tile [n=64][d=64], xor-swizzled
  __shared__ unsigned short Vl[2][64 * 64];  // V^T tile [d=64][n=64], xor-swizzled
  const size_t wh = (size_t)wh_idx;
  const unsigned short* Qb = Qatt + wh * 65536u;
  const unsigned short* Kb = Katt + wh * 65536u;
  const unsigned short* Vb = Vt + wh * 65536u;

  // staging: 512 slots (16B) per tile, 2 per thread: slot = wv*128 + i*64 + lane
  int sl0 = wv * 128 + lane, sl1 = sl0 + 64;
  int r0 = sl0 >> 3, off0 = ((sl0 & 7) ^ (r0 & 7)) * 8;
  int r1 = sl1 >> 3, off1 = ((sl1 & 7) ^ (r1 & 7)) * 8;
  unsigned short* Kd0 = &Kl[0][0] + wv * 1024;  // dst base (wave-uniform), call i adds i*512
  unsigned short* Vd0 = &Vl[0][0] + wv * 1024;

  // issue kt=0 tile loads
  gl_lds16(Kb + (size_t)r0 * 64u + off0, Kd0);
  gl_lds16(Kb + (size_t)r1 * 64u + off1, Kd0 + 512);
  gl_lds16(Vb + (size_t)r0 * 1024u + off0, Vd0);
  gl_lds16(Vb + (size_t)r1 * 1024u + off1, Vd0 + 512);

  int qrow = rb * 128 + wv * 32 + col_l;
  bf16x8 qf[4];
#pragma unroll
  for (int kk = 0; kk < 4; kk++) qf[kk] = *(const bf16x8*)(Qb + (size_t)qrow * 64u + kk * 16 + 8 * half);

  f32x16 oacc[2];
#pragma unroll
  for (int j = 0; j < 2; j++)
#pragma unroll
    for (int r = 0; r < 16; r++) oacc[j][r] = 0.f;
  float lsum = 0.f;

  const int kx = col_l & 7;  // row xor key (row = jb*32+col_l or dblk*32+col_l; 32%8==0)

  for (int kt = 0; kt < 16; ++kt) {
    const unsigned short* Kc = Kl[kt & 1];
    const unsigned short* Vc = Vl[kt & 1];
    __builtin_amdgcn_s_waitcnt(0x0F70);  // vmcnt(0): this wave's kt-tile DMA done
    __syncthreads();                     // all waves' DMA done; prev compute done
    if (kt < 15) {
      unsigned short* Kn = &Kl[(kt + 1) & 1][0] + wv * 1024;
      unsigned short* Vn = &Vl[(kt + 1) & 1][0] + wv * 1024;
      int nk = (kt + 1) * 64;
      gl_lds16(Kb + (size_t)(nk + r0) * 64u + off0, Kn);
      gl_lds16(Kb + (size_t)(nk + r1) * 64u + off1, Kn + 512);
      gl_lds16(Vb + (size_t)r0 * 1024u + nk + off0, Vn);
      gl_lds16(Vb + (size_t)r1 * 1024u + nk + off1, Vn + 512);
    }

    // S^T tile: [64 keys x 32 q], A = K rows, B = Q rows (as cols)
    f32x16 sacc[2];
#pragma unroll
    for (int jb = 0; jb < 2; jb++)
#pragma unroll
      for (int r = 0; r < 16; r++) sacc[jb][r] = 0.f;
#pragma unroll
    for (int jb = 0; jb < 2; jb++) {
      const unsigned short* Krow = Kc + (jb * 32 + col_l) * 64;
#pragma unroll
      for (int kk = 0; kk < 4; kk++) {
        bf16x8 af = *(const bf16x8*)(Krow + (((kk * 2 + half) ^ kx) * 8));
        sacc[jb] = MFMA32(af, qf[kk], sacc[jb]);
      }
    }

    // per 32-key block: exp2 (scale pre-folded into Q) -> pack bf16 -> half-wave exchange -> PV
#pragma unroll
    for (int jb = 0; jb < 2; jb++) {
      float p[16];
#pragma unroll
      for (int r = 0; r < 16; r++) p[r] = __builtin_amdgcn_exp2f(sacc[jb][r]);
      float ps = ((p[0] + p[1]) + (p[2] + p[3])) + ((p[4] + p[5]) + (p[6] + p[7]));
      ps += ((p[8] + p[9]) + (p[10] + p[11])) + ((p[12] + p[13]) + (p[14] + p[15]));
      lsum += ps;
      unsigned int pk[8];
#pragma unroll
      for (int j = 0; j < 8; j++)
        pk[j] = __builtin_amdgcn_perm(__float_as_uint(p[2 * j + 1]), __float_as_uint(p[2 * j]), 0x07060302u);
      // exchange with lane^32 to build A-operand fragments
      unsigned int rA = __shfl_xor((int)(half ? pk[0] : pk[2]), 32);
      unsigned int rB = __shfl_xor((int)(half ? pk[1] : pk[3]), 32);
      unsigned int rC = __shfl_xor((int)(half ? pk[4] : pk[6]), 32);
      unsigned int rD = __shfl_xor((int)(half ? pk[5] : pk[7]), 32);
      u32x4 f0, f1;
      f0[0] = half ? rA : pk[0];
      f0[1] = half ? rB : pk[1];
      f0[2] = half ? pk[2] : rA;
      f0[3] = half ? pk[3] : rB;
      f1[0] = half ? rC : pk[4];
      f1[1] = half ? rD : pk[5];
      f1[2] = half ? pk[6] : rC;
      f1[3] = half ? pk[7] : rD;
      bf16x8 pa0 = __builtin_bit_cast(bf16x8, f0);
      bf16x8 pa1 = __builtin_bit_cast(bf16x8, f1);
#pragma unroll
      for (int dblk = 0; dblk < 2; dblk++) {
        const unsigned short* Vrow = Vc + (dblk * 32 + col_l) * 64;
        bf16x8 v0 = *(const bf16x8*)(Vrow + (((jb * 4 + half) ^ kx) * 8));
        bf16x8 v1 = *(const bf16x8*)(Vrow + (((jb * 4 + 2 + half) ^ kx) * 8));
        oacc[dblk] = MFMA32(pa0, v0, oacc[dblk]);
        oacc[dblk] = MFMA32(pa1, v1, oacc[dblk]);
      }
    }
  }

  float l = lsum + __shfl_xor(lsum, 32);
  float inv = 1.f / l;

  int b = win >> 2, whn = (win >> 1) & 1, wwn = win & 1;
#pragma unroll
  for (int r = 0; r < 16; r++) {
    int qr = ROWOF(r, half);
    float invr = __shfl(inv, qr);
    int ntok = rb * 128 + wv * 32 + qr;
    int h = whn * 32 + (ntok >> 5), w = wwn * 32 + (ntok & 31);
    int s = h * 64 + w;
    size_t rowbase = ((size_t)b * 4096u + s) * 512u + head * 64;
    Oimg[rowbase + col_l] = f2bf(oacc[0][r] * invr);
    Oimg[rowbase + 32 + col_l] = f2bf(oacc[1][r] * invr);
  }
}

// ---------------- output projection + residual: D[o][s], grid (4,32,4) ----------------
// Residual x tile prefetched into registers BEFORE the K-loop (64 batched loads,
// covered by MFMA loop) -> epilogue is add+store only, no vmcnt stalls.
__global__ __launch_bounds__(256, 2) void out_gemm_k(const unsigned short* __restrict__ wo_bf,
                                                     const unsigned short* __restrict__ Oimg,
                                                     const float* __restrict__ bo, const float* __restrict__ x,
                                                     float* __restrict__ out) {
  int b = blockIdx.z;
  int o0 = blockIdx.x * 128, s0 = blockIdx.y * 128;
  __shared__ unsigned short Wl[128 * 72];
  __shared__ unsigned short Xl[128 * 72];
  int t = threadIdx.x, lane = t & 63, wv = t >> 6;
  int col_l = lane & 31, half = lane >> 5;
  int qm = (wv >> 1) * 64, qn = (wv & 1) * 64;

  // batched residual prefetch (issued up front; completes during K-loop)
  float xv[2][2][16];
#pragma unroll
  for (int i = 0; i < 2; i++)
#pragma unroll
    for (int j = 0; j < 2; j++) {
      int s = s0 + qn + 32 * j + col_l;
#pragma unroll
      for (int r = 0; r < 16; r++) {
        int o = o0 + qm + 32 * i + ROWOF(r, half);
        xv[i][j][r] = x[((size_t)b * 512u + o) * 4096u + s];
      }
    }

  f32x16 acc[2][2];
#pragma unroll
  for (int i = 0; i < 2; i++)
#pragma unroll
    for (int j = 0; j < 2; j++)
#pragma unroll
      for (int r = 0; r < 16; r++) acc[i][j][r] = 0.f;

  const unsigned short* ob = Oimg + ((size_t)b * 4096u + s0) * 512u;
  for (int kb = 0; kb < 512; kb += 64) {
    __syncthreads();
    {
      int row = t >> 3, ch = (t & 7) * 8;
#pragma unroll
      for (int p = 0; p < 4; ++p, row += 32) {
        *(uint4*)(Wl + row * 72 + ch) = *(const uint4*)(wo_bf + (size_t)(o0 + row) * 512u + kb + ch);
        *(uint4*)(Xl + row * 72 + ch) = *(const uint4*)(ob + (size_t)row * 512u + kb + ch);
      }
    }
    __syncthreads();
#pragma unroll
    for (int ks = 0; ks < 64; ks += 16) {
      bf16x8 a0 = *(const bf16x8*)(Wl + (qm + col_l) * 72 + ks + 8 * half);
      bf16x8 a1 = *(const bf16x8*)(Wl + (qm + 32 + col_l) * 72 + ks + 8 * half);
      bf16x8 b0 = *(const bf16x8*)(Xl + (qn + col_l) * 72 + ks + 8 * half);
      bf16x8 b1 = *(const bf16x8*)(Xl + (qn + 32 + col_l) * 72 + ks + 8 * half);
      acc[0][0] = MFMA32(a0, b0, acc[0][0]);
      acc[0][1] = MFMA32(a0, b1, acc[0][1]);
      acc[1][0] = MFMA32(a1, b0, acc[1][0]);
      acc[1][1] = MFMA32(a1, b1, acc[1][1]);
    }
  }
#pragma unroll
  for (int i = 0; i < 2; i++)
#pragma unroll
    for (int j = 0; j < 2; j++) {
      int s = s0 + qn + 32 * j + col_l;
#pragma unroll
      for (int r = 0; r < 16; r++) {
        int o = o0 + qm + 32 * i + ROWOF(r, half);
        size_t idx = ((size_t)b * 512u + o) * 4096u + s;
        out[idx] = xv[i][j][r] + acc[i][j][r] + bo[o];
      }
    }
}

extern "C" void kernel_launch(void* const* d_in, const int* in_sizes, int n_in,
                              void* d_out, int out_size, void* d_ws, size_t ws_size,
                              hipStream_t stream) {
  const float* x = (const float*)d_in[0];
  const float* nsc = (const float*)d_in[1];
  const float* nbi = (const float*)d_in[2];
  const float* wq = (const float*)d_in[3];
  const float* bq = (const float*)d_in[4];
  const float* wk = (const float*)d_in[5];
  const float* bk = (const float*)d_in[6];
  const float* wvp = (const float*)d_in[7];
  const float* bv = (const float*)d_in[8];
  const float* wo = (const float*)d_in[9];
  const float* bo = (const float*)d_in[10];
  float* out = (float*)d_out;
  char* ws = (char*)d_ws;

  float* stats = (float*)(ws + OFF_STATS);
  unsigned short* wbf = (unsigned short*)(ws + OFF_W);
  unsigned short* ht = (unsigned short*)(ws + OFF_HT);
  unsigned short* Qatt = (unsigned short*)(ws + OFF_Q);
  unsigned short* Katt = (unsigned short*)(ws + OFF_K);
  unsigned short* Vt = (unsigned short*)(ws + OFF_V);
  unsigned short* Oimg = (unsigned short*)(ws + OFF_O);

  wconv_k<<<dim3(256, 4), 256, 0, stream>>>(wq, wk, wvp, wo, wbf);
  gn_stats_k<<<dim3(128, 8), 256, 0, stream>>>(x, stats);
  gn_apply_k<<<2048, 256, 0, stream>>>(x, nsc, nbi, stats, ht);
  qkv_gemm_k<<<dim3(4, 32, 12), 256, 0, stream>>>(wbf, ht, bq, bk, bv, Qatt, Katt, Vt);
  attn_k<<<dim3(128, 8), 256, 0, stream>>>(Qatt, Katt, Vt, Oimg);
  out_gemm_k<<<dim3(4, 32, 4), 256, 0, stream>>>(wbf + 3u * 262144u, Oimg, bo, x, out);
}